// Round 16
// baseline (10957.670 us; speedup 1.0000x reference)
//
#include <hip/hip_runtime.h>
#include <hip/hip_cooperative_groups.h>

namespace cg = cooperative_groups;

#define T_STEPS 256
// sizes: M=4 N=48 H1=4160 HID=2320 3HID=6960 H2=768 OUT=192 KGIN=52

// ---------------- ws byte-offset layout ----------------
#define O_SLOT  0                  // 256 slots x 128B = 32768
#define O_EPOCH 32768              // 32 epoch replicas x 128B -> 36864
#define O_ZP    36864              // 384 f32 -> 38400
#define O_HF    38400              // 2 x 9280 -> 56960
#define HF_STR  9280
#define O_HB    56960              // 2 x 4672 -> 66304
#define HB_STR  4672
#define O_GI4   66304              // 2320*4 f32 -> 103424
#define O_GH4   103424             // 2320*4 f32 -> 140544
// packed weights: pk[job][kt][lane] 16B fragments, per-wave contiguous streams
#define O_PIH   140544             // 435*130*1024 = 57,907,200 -> 58,047,744
#define O_PHH   58047744           // 435*73*1024  = 32,517,120 -> 90,564,864
#define O_W2B   90564864           // 768*2320*2   =  3,563,520 -> 94,128,384
#define NEED_MIN 94128384
#define O_W1P   94128384           // 4160*56*2    =    465,920 -> 94,594,304
#define NEED_FULL 94594304

#define N_W2  1781760
#define PIN_U4 (130 * 64)          // 8320 uint4 = 133,120 B pinned per block
#define DYN_LDS 133120

// legacy fp32-path offsets (float units) for fallback kernel
#define WS_L1  0
#define WS_H0  4160
#define WS_H1  6480
#define WS_L2  8800
#define WS_V   9568
#define WS_C   12640

typedef __attribute__((ext_vector_type(8))) short bf16x8;
typedef __attribute__((ext_vector_type(4))) float f32x4;
typedef unsigned long long u64t;

__device__ __forceinline__ float wred(float v) {
#pragma unroll
  for (int m = 32; m; m >>= 1) v += __shfl_xor(v, m, 64);
  return v;
}
__device__ __forceinline__ float dot4(float4 a, float4 b) {
  return a.x * b.x + a.y * b.y + a.z * b.z + a.w * b.w;
}
__device__ __forceinline__ float blo(unsigned u) {
  unsigned t = u << 16; return __builtin_bit_cast(float, t);
}
__device__ __forceinline__ float bhi(unsigned u) {
  unsigned t = u & 0xFFFF0000u; return __builtin_bit_cast(float, t);
}
__device__ __forceinline__ float dot8bb(uint4 w, uint4 x) {
  float s;
  s  = blo(w.x) * blo(x.x) + bhi(w.x) * bhi(x.x);
  s += blo(w.y) * blo(x.y) + bhi(w.y) * bhi(x.y);
  s += blo(w.z) * blo(x.z) + bhi(w.z) * bhi(x.z);
  s += blo(w.w) * blo(x.w) + bhi(w.w) * bhi(x.w);
  return s;
}
__device__ __forceinline__ unsigned short f2bf(float f) {  // RNE
  unsigned u = __builtin_bit_cast(unsigned, f);
  unsigned r = u + 0x7FFF + ((u >> 16) & 1);
  return (unsigned short)(r >> 16);
}
__device__ __forceinline__ float u2f_lo(u64t v) {
  unsigned u = (unsigned)(v & 0xFFFFFFFFull);
  return __builtin_bit_cast(float, u);
}
__device__ __forceinline__ float u2f_hi(u64t v) {
  unsigned u = (unsigned)(v >> 32);
  return __builtin_bit_cast(float, u);
}
// non-temporal 16B load via two u64 NT loads (builtin rejects vector-type ptrs)
__device__ __forceinline__ uint4 ntl16(const uint4* p) {
  const u64t* q = (const u64t*)p;
  u64t a = __builtin_nontemporal_load(q);
  u64t b = __builtin_nontemporal_load(q + 1);
  uint4 v;
  v.x = (unsigned)(a & 0xFFFFFFFFull);
  v.y = (unsigned)(a >> 32);
  v.z = (unsigned)(b & 0xFFFFFFFFull);
  v.w = (unsigned)(b >> 32);
  return v;
}

// ---- scoped accessors: cross-block data via coherence point, no invalidates
__device__ __forceinline__ void st_ag_f32(float* p, float v) {
  __hip_atomic_store(p, v, __ATOMIC_RELAXED, __HIP_MEMORY_SCOPE_AGENT);
}
__device__ __forceinline__ float ld_ag_f32(const float* p) {
  return __hip_atomic_load(p, __ATOMIC_RELAXED, __HIP_MEMORY_SCOPE_AGENT);
}
__device__ __forceinline__ void st_ag_u32(unsigned* p, unsigned v) {
  __hip_atomic_store(p, v, __ATOMIC_RELAXED, __HIP_MEMORY_SCOPE_AGENT);
}
__device__ __forceinline__ u64t ld_ag_u64(const u64t* p) {
  return __hip_atomic_load(p, __ATOMIC_RELAXED, __HIP_MEMORY_SCOPE_AGENT);
}

// ---------- line-spread slot barrier ----------
__device__ __forceinline__ void gbar(char* wsb, int bid, unsigned target, int* s_ok) {
  unsigned* slot  = (unsigned*)(wsb + O_SLOT);    // stride 32 u32 = 128B
  unsigned* epoch = (unsigned*)(wsb + O_EPOCH);   // stride 32 u32 = 128B
  const int tid = threadIdx.x;
  __syncthreads();
  if (bid == 0) {
    for (;;) {
      if (tid == 0) *s_ok = 1;
      __syncthreads();
      if (tid >= 1 && tid < 256) {
        if (__hip_atomic_load(&slot[tid * 32], __ATOMIC_RELAXED, __HIP_MEMORY_SCOPE_AGENT) < target)
          *s_ok = 0;
      }
      __syncthreads();
      if (*s_ok) break;
      __builtin_amdgcn_s_sleep(2);
    }
    if (tid < 32)
      __hip_atomic_store(&epoch[tid * 32], target, __ATOMIC_RELEASE, __HIP_MEMORY_SCOPE_AGENT);
    __syncthreads();
  } else {
    if (tid == 0) {
      __hip_atomic_store(&slot[bid * 32], target, __ATOMIC_RELEASE, __HIP_MEMORY_SCOPE_AGENT);
      unsigned* ep = &epoch[(bid & 31) * 32];
      while (__hip_atomic_load(ep, __ATOMIC_RELAXED, __HIP_MEMORY_SCOPE_AGENT) < target)
        __builtin_amdgcn_s_sleep(4);
    }
    __syncthreads();
  }
}

// ---------------- pre-pass kernels ----------------
__global__ __launch_bounds__(256) void k_pack(const float* __restrict__ W,
                                              uint4* __restrict__ dst,
                                              int K, int NKT, int n) {
  int idx = blockIdx.x * 256 + threadIdx.x;
  int stride = gridDim.x * 256;
  for (; idx < n; idx += stride) {
    int l = idx & 63;
    int u = idx >> 6;
    int kt = u % NKT;
    int job = u / NKT;
    int g = job / 145, jt = job - g * 145;
    int row = g * 2320 + jt * 16 + (l & 15);
    int col = kt * 32 + ((l >> 4) << 3);
    const float* src = W + (size_t)row * K + col;
    unsigned short o[8];
    if (col + 7 < K) {
#pragma unroll
      for (int i = 0; i < 8; i++) o[i] = f2bf(src[i]);
    } else {
#pragma unroll
      for (int i = 0; i < 8; i++) o[i] = (col + i < K) ? f2bf(src[i]) : (unsigned short)0;
    }
    uint4 v;
    v.x = (unsigned)o[0] | ((unsigned)o[1] << 16);
    v.y = (unsigned)o[2] | ((unsigned)o[3] << 16);
    v.z = (unsigned)o[4] | ((unsigned)o[5] << 16);
    v.w = (unsigned)o[6] | ((unsigned)o[7] << 16);
    dst[idx] = v;
  }
}
__global__ __launch_bounds__(256) void k_cvt(const float4* __restrict__ src,
                                             ushort4* __restrict__ dst, int n4) {
  int i = blockIdx.x * 256 + threadIdx.x, st = gridDim.x * 256;
  for (; i < n4; i += st) {
    float4 v = src[i];
    ushort4 o;
    o.x = f2bf(v.x); o.y = f2bf(v.y); o.z = f2bf(v.z); o.w = f2bf(v.w);
    dst[i] = o;
  }
}
__global__ __launch_bounds__(256) void k_cvtw1(const float* __restrict__ W1,
                                               unsigned short* __restrict__ dst) {
  int i = blockIdx.x * 256 + threadIdx.x;           // over 4160*56
  if (i < 4160 * 56) {
    int r = i / 56, c = i - r * 56;
    dst[i] = (c < 52) ? f2bf(W1[r * 52 + c]) : (unsigned short)0;
  }
}
__global__ __launch_bounds__(256) void k_h0(const float* __restrict__ h0,
                                            unsigned short* __restrict__ hb0,
                                            unsigned short* __restrict__ hb1) {
  int j = blockIdx.x * 256 + threadIdx.x;
  if (j < 2336) {
    hb1[j] = (j < 2320) ? f2bf(h0[j]) : (unsigned short)0;
    if (j >= 2320) hb0[j] = 0;
  }
}

// ================= main 2-sync kernel (256 blocks x 1024 threads) =================
// R16 = R15 with the NT-load compile fix (ntl16 via 2x u64 nontemporal loads).
// 1. hh weight streams (side==1) NON-TEMPORAL -> stop thrashing L2, so q1-ih
//    streams (~2.9 MB/XCD, fits 4MB L2) become persistent L2 hits.
// 2. h-staging issued at prologue start (latency overlaps small-math chain).
// 3. h/hf publish sliced across the 96 C blocks.
// All numerics bit-identical to R13/R14 -> absmax 0.125 exact.
__global__ __launch_bounds__(1024, 4) void knet2(
    const float* __restrict__ y_seq, const float* __restrict__ x0,
    const float* __restrict__ h0, const float* __restrict__ A,
    const float* __restrict__ Cm, const float* __restrict__ W1,
    const float* __restrict__ b1, const float* __restrict__ b_ih,
    const float* __restrict__ b_hh, const float* __restrict__ b2,
    const float* __restrict__ W3, const float* __restrict__ b3,
    float* __restrict__ out, char* __restrict__ wsb, int use_w1p)
{
  const int tid  = threadIdx.x;
  const int lane = tid & 63;
  const int wav  = tid >> 6;
  const int bid  = blockIdx.x;

  float* zp  = (float*)(wsb + O_ZP);
  float* gi4 = (float*)(wsb + O_GI4);
  float* gh4 = (float*)(wsb + O_GH4);
  const unsigned short* bw2 = (const unsigned short*)(wsb + O_W2B);
  const uint4* w1p = (const uint4*)(wsb + O_W1P);

  extern __shared__ __align__(16) char dynsmem[];
  uint4* pin = (uint4*)dynsmem;                  // 130 kt x 64 lanes, q0 job

  __shared__ __align__(16) uint4 s_l1u[520];     // l1 bf16
  __shared__ __align__(16) uint4 s_h4u[292];     // h bf16 (MFMA operand)
  __shared__ __align__(16) unsigned short s_h2[2336];  // h_new bf16 (C)
  __shared__ float s_part[4][4][16];
  __shared__ __align__(16) unsigned short s_kgb[64];
  __shared__ __align__(16) float s_kgf[52];
  __shared__ float s_innov[48];
  __shared__ float s_a[192];
  __shared__ float s_zred[384];
  __shared__ float s_l2loc[8];
  __shared__ float s_xpost[4], s_xprior[4], s_dx[4];
  __shared__ float s_sc2, s_sc4;
  __shared__ int s_ok;

  // ---- one-time: pin this block's q0 (ih) job weights into LDS ----
  {
    const uint4* src = (const uint4*)(wsb + O_PIH) + (size_t)bid * PIN_U4;
    for (int i = tid; i < PIN_U4; i += 1024) pin[i] = src[i];
  }

  unsigned ep = 0;

  for (int t = 0; t <= T_STEPS; ++t) {
    // ======== prologue: x_post(t) from z-partials(t-1) [all blocks] ========
    if (t == 0) {
      if (tid < 4) s_xpost[tid] = x0[tid];
    } else {
      if (tid < 384) s_zred[tid] = ld_ag_f32(&zp[tid]);   // parallel gather
      __syncthreads();
      if (tid < 4) {
        float z = 0.f;
#pragma unroll 8
        for (int p = 0; p < 96; ++p) z += s_zred[p * 4 + tid];
        float cb = 0.f;
        for (int j = 0; j < 48; ++j) cb += s_innov[j] * b3[tid * 48 + j];
        float xn = s_xprior[tid] + (z + cb) * 1e-4f;
        s_xpost[tid] = xn;
        if (bid == 0) out[tid * T_STEPS + (t - 1)] = xn;
      }
    }
    __syncthreads();
    if (t == T_STEPS) return;

    // ======== stage h(t-1) bf16 into LDS EARLY (latency overlaps small math) ====
    {
      const u64t* hbg = (const u64t*)(wsb + O_HB + ((t + 1) & 1) * HB_STR);
      u64t* dst = (u64t*)s_h4u;
      if (tid < 584) dst[tid] = ld_ag_u64(hbg + tid);
    }

    // ======== small math: x_prior, innov, kg_in ========
    if (tid < 4) {
      float xpr = 0.f;
#pragma unroll
      for (int j = 0; j < 4; j++) xpr += A[tid * 4 + j] * s_xpost[j];
      s_xprior[tid] = xpr;
    }
    __syncthreads();
    if (tid < 48) {
      float yp = Cm[tid * 5 + 4];
#pragma unroll
      for (int j = 0; j < 4; j++) yp += Cm[tid * 5 + j] * s_xprior[j];
      s_innov[tid] = y_seq[tid * T_STEPS + t] - yp;
    }
    if (tid >= 64 && tid < 68) {
      int i = tid - 64;
      s_dx[i] = s_xpost[i] - s_xprior[i];
    }
    __syncthreads();
    if (tid == 0) {
      float s2 = 0.f;
      for (int r = 0; r < 48; r++) s2 += s_innov[r] * s_innov[r];
      s_sc2 = 1.0f / fmaxf(sqrtf(s2), 1e-12f);
      float s4 = 0.f;
      for (int i = 0; i < 4; i++) s4 += s_dx[i] * s_dx[i];
      s_sc4 = 1.0f / fmaxf(sqrtf(s4), 1e-12f);
    }
    __syncthreads();
    if (tid < 64) {
      float v = (tid < 48) ? s_innov[tid] * s_sc2
              : (tid < 52) ? s_dx[tid - 48] * s_sc4 : 0.f;
      s_kgb[tid] = f2bf(v);
      if (tid < 52) s_kgf[tid] = v;
    }
    __syncthreads();

    // ======== l1 = relu(W1 @ kg + b1), redundant per block ========
    if (use_w1p) {
      const uint4* kg4 = (const uint4*)s_kgb;
      for (int r = tid; r < 4160; r += 1024) {
        const uint4* wr = w1p + (size_t)r * 7;
        float acc = b1[r];
#pragma unroll
        for (int c = 0; c < 7; c++) acc += dot8bb(wr[c], kg4[c]);
        ((unsigned short*)s_l1u)[r] = f2bf(fmaxf(acc, 0.f));
      }
    } else {
      const float4* kg4 = (const float4*)s_kgf;
      for (int r = tid; r < 4160; r += 1024) {
        const float4* wr = (const float4*)(W1 + (size_t)r * 52);
        float acc = b1[r];
#pragma unroll
        for (int c = 0; c < 13; c++) acc += dot4(wr[c], kg4[c]);
        ((unsigned short*)s_l1u)[r] = f2bf(fmaxf(acc, 0.f));
      }
    }
    __syncthreads();   // covers l1 writes AND the early h-staging

    // ======== GRU GEMV via MFMA: q0 pinned LDS; q1-3 global 8-deep clamped ====
    {
      const int q  = wav >> 2;        // job slot 0..3
      const int kw = wav & 3;         // k-split
      const int job = bid + 256 * q;
      if (job < 870) {
        const int xoff = lane >> 4;
        f32x4 acc = {0.f, 0.f, 0.f, 0.f};
        if (q == 0) {
          // ---- pinned LDS path (ih job 'bid', all 130 kt resident) ----
          int kbeg = kw * 33, kend = kbeg + 33; if (kend > 130) kend = 130;
          const uint4* xs = s_l1u;
          for (int kt = kbeg; kt < kend; ++kt)
            acc = __builtin_amdgcn_mfma_f32_16x16x32_bf16(
                __builtin_bit_cast(bf16x8, pin[kt * 64 + lane]),
                __builtin_bit_cast(bf16x8, xs[kt * 4 + xoff]), acc, 0, 0, 0);
        } else if (job < 435) {
          // ---- ih global job: NORMAL cached loads ----
          const uint4* xs = s_l1u;
          int kbeg = kw * 33, kend = kbeg + 33; if (kend > 130) kend = 130;
          const uint4* wp = (const uint4*)(wsb + O_PIH) + ((size_t)job * 130 + kbeg) * 64 + lane;
          const int last = kend - kbeg - 1;
          uint4 b0  = wp[0 * 64];
          uint4 b1r = wp[1 * 64];
          uint4 b2r = wp[2 * 64];
          uint4 b3r = wp[3 * 64];
          uint4 b4  = wp[4 * 64];
          uint4 b5  = wp[5 * 64];
          uint4 b6  = wp[6 * 64];
          uint4 b7  = wp[7 * 64];
          int kt = kbeg;
#define GSTEP(P, B) { acc = __builtin_amdgcn_mfma_f32_16x16x32_bf16( \
              __builtin_bit_cast(bf16x8, B), \
              __builtin_bit_cast(bf16x8, xs[(kt + P) * 4 + xoff]), acc, 0, 0, 0); \
              int ri = kt - kbeg + 8 + P; ri = (ri > last) ? last : ri; \
              B = wp[(size_t)ri * 64]; }
          while (kt + 8 <= kend) {
            GSTEP(0, b0) GSTEP(1, b1r) GSTEP(2, b2r) GSTEP(3, b3r)
            GSTEP(4, b4) GSTEP(5, b5)  GSTEP(6, b6)  GSTEP(7, b7)
            kt += 8;
          }
#undef GSTEP
#define TSTEP(P, B) if (kt + P < kend) acc = __builtin_amdgcn_mfma_f32_16x16x32_bf16( \
              __builtin_bit_cast(bf16x8, B), \
              __builtin_bit_cast(bf16x8, xs[(kt + P) * 4 + xoff]), acc, 0, 0, 0);
          TSTEP(0, b0) TSTEP(1, b1r) TSTEP(2, b2r) TSTEP(3, b3r)
          TSTEP(4, b4) TSTEP(5, b5)  TSTEP(6, b6)  TSTEP(7, b7)
#undef TSTEP
        } else {
          // ---- hh global job: NON-TEMPORAL loads ----
          const uint4* xs = s_h4u;
          int kbeg = kw * 19, kend = kbeg + 19; if (kend > 73) kend = 73;
          const uint4* wp = (const uint4*)(wsb + O_PHH) + ((size_t)(job - 435) * 73 + kbeg) * 64 + lane;
          const int last = kend - kbeg - 1;
          uint4 b0  = ntl16(&wp[0 * 64]);
          uint4 b1r = ntl16(&wp[1 * 64]);
          uint4 b2r = ntl16(&wp[2 * 64]);
          uint4 b3r = ntl16(&wp[3 * 64]);
          uint4 b4  = ntl16(&wp[4 * 64]);
          uint4 b5  = ntl16(&wp[5 * 64]);
          uint4 b6  = ntl16(&wp[6 * 64]);
          uint4 b7  = ntl16(&wp[7 * 64]);
          int kt = kbeg;
#define GSTEP(P, B) { acc = __builtin_amdgcn_mfma_f32_16x16x32_bf16( \
              __builtin_bit_cast(bf16x8, B), \
              __builtin_bit_cast(bf16x8, xs[(kt + P) * 4 + xoff]), acc, 0, 0, 0); \
              int ri = kt - kbeg + 8 + P; ri = (ri > last) ? last : ri; \
              B = ntl16(&wp[(size_t)ri * 64]); }
          while (kt + 8 <= kend) {
            GSTEP(0, b0) GSTEP(1, b1r) GSTEP(2, b2r) GSTEP(3, b3r)
            GSTEP(4, b4) GSTEP(5, b5)  GSTEP(6, b6)  GSTEP(7, b7)
            kt += 8;
          }
#undef GSTEP
#define TSTEP(P, B) if (kt + P < kend) acc = __builtin_amdgcn_mfma_f32_16x16x32_bf16( \
              __builtin_bit_cast(bf16x8, B), \
              __builtin_bit_cast(bf16x8, xs[(kt + P) * 4 + xoff]), acc, 0, 0, 0);
          TSTEP(0, b0) TSTEP(1, b1r) TSTEP(2, b2r) TSTEP(3, b3r)
          TSTEP(4, b4) TSTEP(5, b5)  TSTEP(6, b6)  TSTEP(7, b7)
#undef TSTEP
        }
        if ((lane & 15) == 0) {
          int rb = (lane >> 4) * 4;
#pragma unroll
          for (int i = 0; i < 4; i++) s_part[q][kw][rb + i] = acc[i];
        }
      }
    }
    __syncthreads();
    if (tid < 64) {
      int q = tid >> 4, r = tid & 15;
      int job = bid + 256 * q;
      if (job < 870) {
        float s = s_part[q][0][r] + s_part[q][1][r] + s_part[q][2][r] + s_part[q][3][r];
        if (job < 435) {
          int g = job / 145, jt = job - g * 145;
          st_ag_f32(&gi4[(size_t)(jt * 16 + r) * 4 + g], s);
        } else {
          int j2 = job - 435;
          int g = j2 / 145, jt = j2 - g * 145;
          st_ag_f32(&gh4[(size_t)(jt * 16 + r) * 4 + g], s);
        }
      }
    }
    ++ep; gbar(wsb, bid, ep, &s_ok);   // -------- SYNC 1: gi/gh ready --------

    // ======== C: gates (96 blocks, redundant), l2, z-partials ========
    if (bid < 96) {
      float* hf_out = (float*)(wsb + O_HF + (t & 1) * HF_STR);
      unsigned* hb_out32 = (unsigned*)(wsb + O_HB + (t & 1) * HB_STR);
      const float* hf_old = (const float*)(wsb + O_HF + ((t + 1) & 1) * HF_STR);
      const u64t* gi2 = (const u64t*)gi4;
      const u64t* gh2 = (const u64t*)gh4;
      const int jlo = (bid * 2320) / 96, jhi = ((bid + 1) * 2320) / 96;  // hf slice
      for (int j = tid; j < 2320; j += 1024) {
        u64t ia = ld_ag_u64(&gi2[(size_t)j * 2]);
        u64t ib = ld_ag_u64(&gi2[(size_t)j * 2 + 1]);
        u64t ha = ld_ag_u64(&gh2[(size_t)j * 2]);
        u64t hb = ld_ag_u64(&gh2[(size_t)j * 2 + 1]);
        float ir = u2f_lo(ia) + b_ih[j];
        float iz = u2f_hi(ia) + b_ih[2320 + j];
        float ig = u2f_lo(ib) + b_ih[4640 + j];
        float hr = u2f_lo(ha) + b_hh[j];
        float hz = u2f_hi(ha) + b_hh[2320 + j];
        float hg = u2f_lo(hb) + b_hh[4640 + j];
        float rr = 1.f / (1.f + expf(-(ir + hr)));
        float zz = 1.f / (1.f + expf(-(iz + hz)));
        float gg = tanhf(ig + rr * hg);
        float hold = (t == 0) ? h0[j] : ld_ag_f32(&hf_old[j]);
        float hn = (1.f - zz) * gg + zz * hold;
        s_h2[j] = f2bf(hn);
        if (j >= jlo && j < jhi) st_ag_f32(&hf_out[j], hn);   // sliced hf publish
      }
      if (tid < 16) s_h2[2320 + tid] = 0;   // keep K-pad zero
      __syncthreads();
      // publish h_new bf16: SLICED across the 96 C blocks (identical values)
      {
        const int wlo = (bid * 1168) / 96, whi = ((bid + 1) * 1168) / 96;
        if (tid < whi - wlo) {
          int w = wlo + tid;
          unsigned v = (unsigned)s_h2[2 * w] | ((unsigned)s_h2[2 * w + 1] << 16);
          st_ag_u32(hb_out32 + w, v);
        }
      }
      // l2 rows (8 per block), bf16 VALU dot from LDS
      if (wav < 8) {
        const int row = bid * 8 + wav;
        const uint4* wr = (const uint4*)(bw2 + (size_t)row * 2320);
        const uint4* hx = (const uint4*)s_h2;
        float acc = 0.f;
        for (int k = lane; k < 290; k += 64) acc += dot8bb(wr[k], hx[k]);
        acc = wred(acc);
        if (lane == 0) s_l2loc[wav] = fmaxf(acc + b2[row], 0.f);
      }
      __syncthreads();
      // z-partials
      if (tid < 192) {
        const float* w3r = W3 + (size_t)tid * 768 + bid * 8;
        float a = 0.f;
#pragma unroll
        for (int r = 0; r < 8; r++) a += w3r[r] * s_l2loc[r];
        s_a[tid] = a * s_innov[tid % 48];
      }
      __syncthreads();
      if (tid < 4) {
        float zv = 0.f;
        for (int j = 0; j < 48; j++) zv += s_a[tid * 48 + j];
        st_ag_f32(&zp[bid * 4 + tid], zv);
      }
    }
    ++ep; gbar(wsb, bid, ep, &s_ok);   // -------- SYNC 2: h/l2/z ready --------
  }
}

// ================= cooperative fp32 kernel (proven fallback) =================
__global__ __launch_bounds__(256, 2) void knet(
    const float* __restrict__ y_seq, const float* __restrict__ x0,
    const float* __restrict__ h0, const float* __restrict__ A,
    const float* __restrict__ Cm, const float* __restrict__ W1,
    const float* __restrict__ b1, const float* __restrict__ W_ih,
    const float* __restrict__ W_hh, const float* __restrict__ b_ih,
    const float* __restrict__ b_hh, const float* __restrict__ W2,
    const float* __restrict__ b2, const float* __restrict__ W3,
    const float* __restrict__ b3, float* __restrict__ out,
    float* __restrict__ ws)
{
  cg::grid_group grid = cg::this_grid();
  const int tid = threadIdx.x, lane = tid & 63, wav = tid >> 6, bid = blockIdx.x;
  const int gt = bid * 256 + tid, wave_g = bid * 4 + wav, NW = gridDim.x * 4;

  __shared__ __align__(16) float4 s_buf4[1040];
  __shared__ __align__(16) float4 s_h4[580];
  __shared__ __align__(16) float s_kgin[52];
  __shared__ float s_innov[48];
  __shared__ float s_xpost[4], s_xprior[4], s_dx[4];
  __shared__ float s_sc2, s_sc4;

  for (int t = 0; t <= T_STEPS; ++t) {
    if (t == 0) {
      if (tid < 4) s_xpost[tid] = x0[tid];
    } else {
      const float4* vv  = (const float4*)(ws + WS_V + wav * 768);
      const float4* l2v = (const float4*)(ws + WS_L2);
      float acc = 0.f;
      for (int k = lane; k < 192; k += 64) acc += dot4(vv[k], l2v[k]);
      acc = wred(acc);
      if (lane == 0)
        s_xpost[wav] = s_xprior[wav] + (acc + ws[WS_C + wav]) * 1e-4f;
    }
    __syncthreads();
    if (bid == 0 && t > 0 && tid < 4) out[tid * T_STEPS + (t - 1)] = s_xpost[tid];
    if (t == T_STEPS) return;

    if (tid < 4) {
      float xp = 0.f;
#pragma unroll
      for (int j = 0; j < 4; j++) xp += A[tid * 4 + j] * s_xpost[j];
      s_xprior[tid] = xp;
    }
    __syncthreads();
    if (tid < 48) {
      float yp = Cm[tid * 5 + 4];
#pragma unroll
      for (int j = 0; j < 4; j++) yp += Cm[tid * 5 + j] * s_xprior[j];
      s_innov[tid] = y_seq[tid * T_STEPS + t] - yp;
    }
    if (tid >= 64 && tid < 68) {
      int i = tid - 64;
      s_dx[i] = s_xpost[i] - s_xprior[i];
    }
    __syncthreads();
    if (tid == 0) {
      float s2 = 0.f;
      for (int r = 0; r < 48; r++) s2 += s_innov[r] * s_innov[r];
      s_sc2 = 1.0f / fmaxf(sqrtf(s2), 1e-12f);
      float s4 = 0.f;
      for (int i = 0; i < 4; i++) s4 += s_dx[i] * s_dx[i];
      s_sc4 = 1.0f / fmaxf(sqrtf(s4), 1e-12f);
    }
    __syncthreads();
    if (tid < 48) s_kgin[tid] = s_innov[tid] * s_sc2;
    else if (tid < 52) s_kgin[tid] = s_dx[tid - 48] * s_sc4;
    __syncthreads();

    if (gt < 4160) {
      const float4* wr  = (const float4*)(W1 + (size_t)gt * 52);
      const float4* kg4 = (const float4*)s_kgin;
      float acc = b1[gt];
#pragma unroll
      for (int k = 0; k < 13; k++) acc += dot4(wr[k], kg4[k]);
      ws[WS_L1 + gt] = fmaxf(acc, 0.f);
    }
    grid.sync();

    {
      const float* h_old = (t == 0) ? h0 : (ws + (((t & 1) == 0) ? WS_H0 : WS_H1));
      float* h_new = ws + (((t & 1) == 0) ? WS_H1 : WS_H0);
      const float4* l1g = (const float4*)(ws + WS_L1);
      for (int i = tid; i < 1040; i += 256) s_buf4[i] = l1g[i];
      const float4* hog = (const float4*)h_old;
      for (int i = tid; i < 580; i += 256) s_h4[i] = hog[i];
      __syncthreads();
      const float* s_h = (const float*)s_h4;

      for (int j = wave_g; j < 2320; j += NW) {
        const float4* r0 = (const float4*)(W_ih + (size_t)j * 4160);
        const float4* r1 = (const float4*)(W_ih + (size_t)(j + 2320) * 4160);
        const float4* r2 = (const float4*)(W_ih + (size_t)(j + 4640) * 4160);
        float a0 = 0.f, a1 = 0.f, a2 = 0.f;
#pragma unroll 4
        for (int k = lane; k < 1040; k += 64) {
          float4 x = s_buf4[k];
          a0 += dot4(r0[k], x); a1 += dot4(r1[k], x); a2 += dot4(r2[k], x);
        }
        const float4* q0 = (const float4*)(W_hh + (size_t)j * 2320);
        const float4* q1 = (const float4*)(W_hh + (size_t)(j + 2320) * 2320);
        const float4* q2 = (const float4*)(W_hh + (size_t)(j + 4640) * 2320);
        float c0 = 0.f, c1 = 0.f, c2 = 0.f;
#pragma unroll 4
        for (int k = lane; k < 580; k += 64) {
          float4 x = s_h4[k];
          c0 += dot4(q0[k], x); c1 += dot4(q1[k], x); c2 += dot4(q2[k], x);
        }
        a0 = wred(a0); a1 = wred(a1); a2 = wred(a2);
        c0 = wred(c0); c1 = wred(c1); c2 = wred(c2);
        if (lane == 0) {
          float ir = a0 + b_ih[j], iz = a1 + b_ih[j + 2320], ig = a2 + b_ih[j + 4640];
          float hr = c0 + b_hh[j], hz = c1 + b_hh[j + 2320], hg = c2 + b_hh[j + 4640];
          float rr = 1.f / (1.f + expf(-(ir + hr)));
          float zz = 1.f / (1.f + expf(-(iz + hz)));
          float gg = tanhf(ig + rr * hg);
          h_new[j] = (1.f - zz) * gg + zz * s_h[j];
        }
      }
    }
    grid.sync();

    {
      const float* h_new = ws + (((t & 1) == 0) ? WS_H1 : WS_H0);
      const float4* hv = (const float4*)h_new;
      for (int i = tid; i < 580; i += 256) s_buf4[i] = hv[i];
      __syncthreads();

      if (gt < 3072) {
        int i = gt / 768, cc = gt - i * 768;
        const float* wcol = W3 + (size_t)(i * 48) * 768 + cc;
        float acc = 0.f;
#pragma unroll 8
        for (int j = 0; j < 48; j++) acc += s_innov[j] * wcol[(size_t)j * 768];
        ws[WS_V + gt] = acc;
      } else if (gt < 3076) {
        int i = gt - 3072;
        float acc = 0.f;
        for (int j = 0; j < 48; j++) acc += s_innov[j] * b3[i * 48 + j];
        ws[WS_C + i] = acc;
      }

      for (int task = wave_g; task < 768; task += NW) {
        const float4* row = (const float4*)(W2 + (size_t)task * 2320);
        float acc = 0.f;
#pragma unroll 4
        for (int k = lane; k < 580; k += 64) acc += dot4(row[k], s_buf4[k]);
        acc = wred(acc);
        if (lane == 0) ws[WS_L2 + task] = fmaxf(acc + b2[task], 0.f);
      }
    }
    grid.sync();
  }
}

extern "C" void kernel_launch(void* const* d_in, const int* in_sizes, int n_in,
                              void* d_out, int out_size, void* d_ws, size_t ws_size,
                              hipStream_t stream) {
  const float* y_seq = (const float*)d_in[0];
  const float* x0    = (const float*)d_in[1];
  const float* h0    = (const float*)d_in[2];
  const float* A     = (const float*)d_in[3];
  const float* Cm    = (const float*)d_in[4];
  const float* W1    = (const float*)d_in[5];
  const float* b1    = (const float*)d_in[6];
  const float* W_ih  = (const float*)d_in[7];
  const float* W_hh  = (const float*)d_in[8];
  const float* b_ih  = (const float*)d_in[9];
  const float* b_hh  = (const float*)d_in[10];
  const float* W2    = (const float*)d_in[11];
  const float* b2    = (const float*)d_in[12];
  const float* W3    = (const float*)d_in[13];
  const float* b3    = (const float*)d_in[14];
  float* out = (float*)d_out;
  float* ws  = (float*)d_ws;
  char* wsb  = (char*)d_ws;

  if (ws_size >= NEED_MIN) {
    int use_w1p = (ws_size >= NEED_FULL) ? 1 : 0;
    hipFuncSetAttribute(reinterpret_cast<const void*>(knet2),
                        hipFuncAttributeMaxDynamicSharedMemorySize, DYN_LDS + 2048);
    hipMemsetAsync(wsb + O_SLOT, 0, 36864, stream);   // slots + epoch replicas
    k_pack<<<8192, 256, 0, stream>>>(W_ih, (uint4*)(wsb + O_PIH),
                                     4160, 130, 435 * 130 * 64);
    k_pack<<<8192, 256, 0, stream>>>(W_hh, (uint4*)(wsb + O_PHH),
                                     2320, 73, 435 * 73 * 64);
    k_cvt<<<512, 256, 0, stream>>>((const float4*)W2,
                                   (ushort4*)(wsb + O_W2B), N_W2 / 4);
    if (use_w1p)
      k_cvtw1<<<(4160 * 56 + 255) / 256, 256, 0, stream>>>(
          W1, (unsigned short*)(wsb + O_W1P));
    k_h0<<<10, 256, 0, stream>>>(h0, (unsigned short*)(wsb + O_HB),
                                 (unsigned short*)(wsb + O_HB + HB_STR));

    void* args[] = { &y_seq, &x0, &h0, &A, &Cm, &W1, &b1, &b_ih, &b_hh,
                     &b2, &W3, &b3, &out, &wsb, &use_w1p };
    hipError_t err = hipLaunchCooperativeKernel(
        reinterpret_cast<void*>(knet2), dim3(256), dim3(1024), args, DYN_LDS, stream);
    if (err == hipSuccess) return;
  }

  {
    void* args[] = { &y_seq, &x0, &h0, &A, &Cm, &W1, &b1, &W_ih, &W_hh,
                     &b_ih, &b_hh, &W2, &b2, &W3, &b3, &out, &ws };
    hipLaunchCooperativeKernel(
        reinterpret_cast<void*>(knet), dim3(256), dim3(256), args, 0, stream);
  }
}

// Round 17
// 10825.220 us; speedup vs baseline: 1.0122x; 1.0122x over previous
//
#include <hip/hip_runtime.h>
#include <hip/hip_cooperative_groups.h>

namespace cg = cooperative_groups;

#define T_STEPS 256
// sizes: M=4 N=48 H1=4160 HID=2320 3HID=6960 H2=768 OUT=192 KGIN=52

// ---------------- ws byte-offset layout ----------------
#define O_SLOT  0                  // 256 slots x 128B = 32768
#define O_EPOCH 32768              // 32 epoch replicas x 128B -> 36864
#define O_ZP    36864              // 384 f32 -> 38400
#define O_HF    38400              // 2 x 9280 -> 56960
#define HF_STR  9280
#define O_HB    56960              // 2 x 4672 -> 66304
#define HB_STR  4672
#define O_GI4   66304              // 2320*4 f32 -> 103424
#define O_GH4   103424             // 2320*4 f32 -> 140544
// packed weights: pk[job][kt][lane] 16B fragments, per-wave contiguous streams
#define O_PIH   140544             // 435*130*1024 = 57,907,200 -> 58,047,744
#define O_PHH   58047744           // 435*73*1024  = 32,517,120 -> 90,564,864
#define O_W2B   90564864           // 768*2320*2   =  3,563,520 -> 94,128,384
#define NEED_MIN 94128384
#define O_W1P   94128384           // 4160*56*2    =    465,920 -> 94,594,304
#define NEED_FULL 94594304

#define N_W2  1781760
#define PIN_U4 (130 * 64)          // 8320 uint4 = 133,120 B pinned per block
#define DYN_LDS 133120

// legacy fp32-path offsets (float units) for fallback kernel
#define WS_L1  0
#define WS_H0  4160
#define WS_H1  6480
#define WS_L2  8800
#define WS_V   9568
#define WS_C   12640

typedef __attribute__((ext_vector_type(8))) short bf16x8;
typedef __attribute__((ext_vector_type(4))) float f32x4;
typedef unsigned long long u64t;

__device__ __forceinline__ float wred(float v) {
#pragma unroll
  for (int m = 32; m; m >>= 1) v += __shfl_xor(v, m, 64);
  return v;
}
__device__ __forceinline__ float dot4(float4 a, float4 b) {
  return a.x * b.x + a.y * b.y + a.z * b.z + a.w * b.w;
}
__device__ __forceinline__ float blo(unsigned u) {
  unsigned t = u << 16; return __builtin_bit_cast(float, t);
}
__device__ __forceinline__ float bhi(unsigned u) {
  unsigned t = u & 0xFFFF0000u; return __builtin_bit_cast(float, t);
}
__device__ __forceinline__ float dot8bb(uint4 w, uint4 x) {
  float s;
  s  = blo(w.x) * blo(x.x) + bhi(w.x) * bhi(x.x);
  s += blo(w.y) * blo(x.y) + bhi(w.y) * bhi(x.y);
  s += blo(w.z) * blo(x.z) + bhi(w.z) * bhi(x.z);
  s += blo(w.w) * blo(x.w) + bhi(w.w) * bhi(x.w);
  return s;
}
__device__ __forceinline__ unsigned short f2bf(float f) {  // RNE
  unsigned u = __builtin_bit_cast(unsigned, f);
  unsigned r = u + 0x7FFF + ((u >> 16) & 1);
  return (unsigned short)(r >> 16);
}
__device__ __forceinline__ float u2f_lo(u64t v) {
  unsigned u = (unsigned)(v & 0xFFFFFFFFull);
  return __builtin_bit_cast(float, u);
}
__device__ __forceinline__ float u2f_hi(u64t v) {
  unsigned u = (unsigned)(v >> 32);
  return __builtin_bit_cast(float, u);
}

// ---- scoped accessors: cross-block data via coherence point, no invalidates
__device__ __forceinline__ void st_ag_f32(float* p, float v) {
  __hip_atomic_store(p, v, __ATOMIC_RELAXED, __HIP_MEMORY_SCOPE_AGENT);
}
__device__ __forceinline__ float ld_ag_f32(const float* p) {
  return __hip_atomic_load(p, __ATOMIC_RELAXED, __HIP_MEMORY_SCOPE_AGENT);
}
__device__ __forceinline__ void st_ag_u32(unsigned* p, unsigned v) {
  __hip_atomic_store(p, v, __ATOMIC_RELAXED, __HIP_MEMORY_SCOPE_AGENT);
}
__device__ __forceinline__ u64t ld_ag_u64(const u64t* p) {
  return __hip_atomic_load(p, __ATOMIC_RELAXED, __HIP_MEMORY_SCOPE_AGENT);
}

// ---------- line-spread slot barrier ----------
__device__ __forceinline__ void gbar(char* wsb, int bid, unsigned target, int* s_ok) {
  unsigned* slot  = (unsigned*)(wsb + O_SLOT);    // stride 32 u32 = 128B
  unsigned* epoch = (unsigned*)(wsb + O_EPOCH);   // stride 32 u32 = 128B
  const int tid = threadIdx.x;
  __syncthreads();
  if (bid == 0) {
    for (;;) {
      if (tid == 0) *s_ok = 1;
      __syncthreads();
      if (tid >= 1 && tid < 256) {
        if (__hip_atomic_load(&slot[tid * 32], __ATOMIC_RELAXED, __HIP_MEMORY_SCOPE_AGENT) < target)
          *s_ok = 0;
      }
      __syncthreads();
      if (*s_ok) break;
      __builtin_amdgcn_s_sleep(2);
    }
    if (tid < 32)
      __hip_atomic_store(&epoch[tid * 32], target, __ATOMIC_RELEASE, __HIP_MEMORY_SCOPE_AGENT);
    __syncthreads();
  } else {
    if (tid == 0) {
      __hip_atomic_store(&slot[bid * 32], target, __ATOMIC_RELEASE, __HIP_MEMORY_SCOPE_AGENT);
      unsigned* ep = &epoch[(bid & 31) * 32];
      while (__hip_atomic_load(ep, __ATOMIC_RELAXED, __HIP_MEMORY_SCOPE_AGENT) < target)
        __builtin_amdgcn_s_sleep(4);
    }
    __syncthreads();
  }
}

// ---------------- pre-pass kernels ----------------
__global__ __launch_bounds__(256) void k_pack(const float* __restrict__ W,
                                              uint4* __restrict__ dst,
                                              int K, int NKT, int n) {
  int idx = blockIdx.x * 256 + threadIdx.x;
  int stride = gridDim.x * 256;
  for (; idx < n; idx += stride) {
    int l = idx & 63;
    int u = idx >> 6;
    int kt = u % NKT;
    int job = u / NKT;
    int g = job / 145, jt = job - g * 145;
    int row = g * 2320 + jt * 16 + (l & 15);
    int col = kt * 32 + ((l >> 4) << 3);
    const float* src = W + (size_t)row * K + col;
    unsigned short o[8];
    if (col + 7 < K) {
#pragma unroll
      for (int i = 0; i < 8; i++) o[i] = f2bf(src[i]);
    } else {
#pragma unroll
      for (int i = 0; i < 8; i++) o[i] = (col + i < K) ? f2bf(src[i]) : (unsigned short)0;
    }
    uint4 v;
    v.x = (unsigned)o[0] | ((unsigned)o[1] << 16);
    v.y = (unsigned)o[2] | ((unsigned)o[3] << 16);
    v.z = (unsigned)o[4] | ((unsigned)o[5] << 16);
    v.w = (unsigned)o[6] | ((unsigned)o[7] << 16);
    dst[idx] = v;
  }
}
__global__ __launch_bounds__(256) void k_cvt(const float4* __restrict__ src,
                                             ushort4* __restrict__ dst, int n4) {
  int i = blockIdx.x * 256 + threadIdx.x, st = gridDim.x * 256;
  for (; i < n4; i += st) {
    float4 v = src[i];
    ushort4 o;
    o.x = f2bf(v.x); o.y = f2bf(v.y); o.z = f2bf(v.z); o.w = f2bf(v.w);
    dst[i] = o;
  }
}
__global__ __launch_bounds__(256) void k_cvtw1(const float* __restrict__ W1,
                                               unsigned short* __restrict__ dst) {
  int i = blockIdx.x * 256 + threadIdx.x;           // over 4160*56
  if (i < 4160 * 56) {
    int r = i / 56, c = i - r * 56;
    dst[i] = (c < 52) ? f2bf(W1[r * 52 + c]) : (unsigned short)0;
  }
}
__global__ __launch_bounds__(256) void k_h0(const float* __restrict__ h0,
                                            unsigned short* __restrict__ hb0,
                                            unsigned short* __restrict__ hb1) {
  int j = blockIdx.x * 256 + threadIdx.x;
  if (j < 2336) {
    hb1[j] = (j < 2320) ? f2bf(h0[j]) : (unsigned short)0;
    if (j >= 2320) hb0[j] = 0;
  }
}

// ================= main 2-sync kernel (256 blocks x 1024 threads) =================
// R17 = R13 (best, 10.33ms) + the two harmless R16 changes, NT reverted:
// 1. h-staging issued at prologue start (latency overlaps small-math chain).
// 2. h/hf publish sliced across the 96 C blocks.
// hh loads back to plain cached uint4 (ntl16's 2x-u64 overhead caused R16's +6%).
__global__ __launch_bounds__(1024, 4) void knet2(
    const float* __restrict__ y_seq, const float* __restrict__ x0,
    const float* __restrict__ h0, const float* __restrict__ A,
    const float* __restrict__ Cm, const float* __restrict__ W1,
    const float* __restrict__ b1, const float* __restrict__ b_ih,
    const float* __restrict__ b_hh, const float* __restrict__ b2,
    const float* __restrict__ W3, const float* __restrict__ b3,
    float* __restrict__ out, char* __restrict__ wsb, int use_w1p)
{
  const int tid  = threadIdx.x;
  const int lane = tid & 63;
  const int wav  = tid >> 6;
  const int bid  = blockIdx.x;

  float* zp  = (float*)(wsb + O_ZP);
  float* gi4 = (float*)(wsb + O_GI4);
  float* gh4 = (float*)(wsb + O_GH4);
  const unsigned short* bw2 = (const unsigned short*)(wsb + O_W2B);
  const uint4* w1p = (const uint4*)(wsb + O_W1P);

  extern __shared__ __align__(16) char dynsmem[];
  uint4* pin = (uint4*)dynsmem;                  // 130 kt x 64 lanes, q0 job

  __shared__ __align__(16) uint4 s_l1u[520];     // l1 bf16
  __shared__ __align__(16) uint4 s_h4u[292];     // h bf16 (MFMA operand)
  __shared__ __align__(16) unsigned short s_h2[2336];  // h_new bf16 (C)
  __shared__ float s_part[4][4][16];
  __shared__ __align__(16) unsigned short s_kgb[64];
  __shared__ __align__(16) float s_kgf[52];
  __shared__ float s_innov[48];
  __shared__ float s_a[192];
  __shared__ float s_zred[384];
  __shared__ float s_l2loc[8];
  __shared__ float s_xpost[4], s_xprior[4], s_dx[4];
  __shared__ float s_sc2, s_sc4;
  __shared__ int s_ok;

  // ---- one-time: pin this block's q0 (ih) job weights into LDS ----
  {
    const uint4* src = (const uint4*)(wsb + O_PIH) + (size_t)bid * PIN_U4;
    for (int i = tid; i < PIN_U4; i += 1024) pin[i] = src[i];
  }

  unsigned ep = 0;

  for (int t = 0; t <= T_STEPS; ++t) {
    // ======== prologue: x_post(t) from z-partials(t-1) [all blocks] ========
    if (t == 0) {
      if (tid < 4) s_xpost[tid] = x0[tid];
    } else {
      if (tid < 384) s_zred[tid] = ld_ag_f32(&zp[tid]);   // parallel gather
      __syncthreads();
      if (tid < 4) {
        float z = 0.f;
#pragma unroll 8
        for (int p = 0; p < 96; ++p) z += s_zred[p * 4 + tid];
        float cb = 0.f;
        for (int j = 0; j < 48; ++j) cb += s_innov[j] * b3[tid * 48 + j];
        float xn = s_xprior[tid] + (z + cb) * 1e-4f;
        s_xpost[tid] = xn;
        if (bid == 0) out[tid * T_STEPS + (t - 1)] = xn;
      }
    }
    __syncthreads();
    if (t == T_STEPS) return;

    // ======== stage h(t-1) bf16 into LDS EARLY (latency overlaps small math) ====
    {
      const u64t* hbg = (const u64t*)(wsb + O_HB + ((t + 1) & 1) * HB_STR);
      u64t* dst = (u64t*)s_h4u;
      if (tid < 584) dst[tid] = ld_ag_u64(hbg + tid);
    }

    // ======== small math: x_prior, innov, kg_in ========
    if (tid < 4) {
      float xpr = 0.f;
#pragma unroll
      for (int j = 0; j < 4; j++) xpr += A[tid * 4 + j] * s_xpost[j];
      s_xprior[tid] = xpr;
    }
    __syncthreads();
    if (tid < 48) {
      float yp = Cm[tid * 5 + 4];
#pragma unroll
      for (int j = 0; j < 4; j++) yp += Cm[tid * 5 + j] * s_xprior[j];
      s_innov[tid] = y_seq[tid * T_STEPS + t] - yp;
    }
    if (tid >= 64 && tid < 68) {
      int i = tid - 64;
      s_dx[i] = s_xpost[i] - s_xprior[i];
    }
    __syncthreads();
    if (tid == 0) {
      float s2 = 0.f;
      for (int r = 0; r < 48; r++) s2 += s_innov[r] * s_innov[r];
      s_sc2 = 1.0f / fmaxf(sqrtf(s2), 1e-12f);
      float s4 = 0.f;
      for (int i = 0; i < 4; i++) s4 += s_dx[i] * s_dx[i];
      s_sc4 = 1.0f / fmaxf(sqrtf(s4), 1e-12f);
    }
    __syncthreads();
    if (tid < 64) {
      float v = (tid < 48) ? s_innov[tid] * s_sc2
              : (tid < 52) ? s_dx[tid - 48] * s_sc4 : 0.f;
      s_kgb[tid] = f2bf(v);
      if (tid < 52) s_kgf[tid] = v;
    }
    __syncthreads();

    // ======== l1 = relu(W1 @ kg + b1), redundant per block ========
    if (use_w1p) {
      const uint4* kg4 = (const uint4*)s_kgb;
      for (int r = tid; r < 4160; r += 1024) {
        const uint4* wr = w1p + (size_t)r * 7;
        float acc = b1[r];
#pragma unroll
        for (int c = 0; c < 7; c++) acc += dot8bb(wr[c], kg4[c]);
        ((unsigned short*)s_l1u)[r] = f2bf(fmaxf(acc, 0.f));
      }
    } else {
      const float4* kg4 = (const float4*)s_kgf;
      for (int r = tid; r < 4160; r += 1024) {
        const float4* wr = (const float4*)(W1 + (size_t)r * 52);
        float acc = b1[r];
#pragma unroll
        for (int c = 0; c < 13; c++) acc += dot4(wr[c], kg4[c]);
        ((unsigned short*)s_l1u)[r] = f2bf(fmaxf(acc, 0.f));
      }
    }
    __syncthreads();   // covers l1 writes AND the early h-staging

    // ======== GRU GEMV via MFMA: q0 pinned LDS; q1-3 global 8-deep clamped ====
    {
      const int q  = wav >> 2;        // job slot 0..3
      const int kw = wav & 3;         // k-split
      const int job = bid + 256 * q;
      if (job < 870) {
        const int xoff = lane >> 4;
        f32x4 acc = {0.f, 0.f, 0.f, 0.f};
        if (q == 0) {
          // ---- pinned LDS path (ih job 'bid', all 130 kt resident) ----
          int kbeg = kw * 33, kend = kbeg + 33; if (kend > 130) kend = 130;
          const uint4* xs = s_l1u;
          for (int kt = kbeg; kt < kend; ++kt)
            acc = __builtin_amdgcn_mfma_f32_16x16x32_bf16(
                __builtin_bit_cast(bf16x8, pin[kt * 64 + lane]),
                __builtin_bit_cast(bf16x8, xs[kt * 4 + xoff]), acc, 0, 0, 0);
        } else {
          const int side = (job < 435) ? 0 : 1;
          const uint4* xs;
          const uint4* wp;
          int kbeg, kend;
          if (side == 0) {
            xs = s_l1u;
            kbeg = kw * 33; kend = kbeg + 33; if (kend > 130) kend = 130;
            wp = (const uint4*)(wsb + O_PIH) + ((size_t)job * 130 + kbeg) * 64 + lane;
          } else {
            xs = s_h4u;
            kbeg = kw * 19; kend = kbeg + 19; if (kend > 73) kend = 73;
            wp = (const uint4*)(wsb + O_PHH) + ((size_t)(job - 435) * 73 + kbeg) * 64 + lane;
          }
          const int last = kend - kbeg - 1;   // last valid local unit
          uint4 b0  = wp[0 * 64];
          uint4 b1r = wp[1 * 64];
          uint4 b2r = wp[2 * 64];
          uint4 b3r = wp[3 * 64];
          uint4 b4  = wp[4 * 64];
          uint4 b5  = wp[5 * 64];
          uint4 b6  = wp[6 * 64];
          uint4 b7  = wp[7 * 64];
          int kt = kbeg;
#define GSTEP(P, B) { acc = __builtin_amdgcn_mfma_f32_16x16x32_bf16( \
              __builtin_bit_cast(bf16x8, B), \
              __builtin_bit_cast(bf16x8, xs[(kt + P) * 4 + xoff]), acc, 0, 0, 0); \
              int ri = kt - kbeg + 8 + P; ri = (ri > last) ? last : ri; \
              B = wp[(size_t)ri * 64]; }
          while (kt + 8 <= kend) {
            GSTEP(0, b0) GSTEP(1, b1r) GSTEP(2, b2r) GSTEP(3, b3r)
            GSTEP(4, b4) GSTEP(5, b5)  GSTEP(6, b6)  GSTEP(7, b7)
            kt += 8;
          }
#undef GSTEP
#define TSTEP(P, B) if (kt + P < kend) acc = __builtin_amdgcn_mfma_f32_16x16x32_bf16( \
              __builtin_bit_cast(bf16x8, B), \
              __builtin_bit_cast(bf16x8, xs[(kt + P) * 4 + xoff]), acc, 0, 0, 0);
          TSTEP(0, b0) TSTEP(1, b1r) TSTEP(2, b2r) TSTEP(3, b3r)
          TSTEP(4, b4) TSTEP(5, b5)  TSTEP(6, b6)  TSTEP(7, b7)
#undef TSTEP
        }
        if ((lane & 15) == 0) {
          int rb = (lane >> 4) * 4;
#pragma unroll
          for (int i = 0; i < 4; i++) s_part[q][kw][rb + i] = acc[i];
        }
      }
    }
    __syncthreads();
    if (tid < 64) {
      int q = tid >> 4, r = tid & 15;
      int job = bid + 256 * q;
      if (job < 870) {
        float s = s_part[q][0][r] + s_part[q][1][r] + s_part[q][2][r] + s_part[q][3][r];
        if (job < 435) {
          int g = job / 145, jt = job - g * 145;
          st_ag_f32(&gi4[(size_t)(jt * 16 + r) * 4 + g], s);
        } else {
          int j2 = job - 435;
          int g = j2 / 145, jt = j2 - g * 145;
          st_ag_f32(&gh4[(size_t)(jt * 16 + r) * 4 + g], s);
        }
      }
    }
    ++ep; gbar(wsb, bid, ep, &s_ok);   // -------- SYNC 1: gi/gh ready --------

    // ======== C: gates (96 blocks, redundant), l2, z-partials ========
    if (bid < 96) {
      float* hf_out = (float*)(wsb + O_HF + (t & 1) * HF_STR);
      unsigned* hb_out32 = (unsigned*)(wsb + O_HB + (t & 1) * HB_STR);
      const float* hf_old = (const float*)(wsb + O_HF + ((t + 1) & 1) * HF_STR);
      const u64t* gi2 = (const u64t*)gi4;
      const u64t* gh2 = (const u64t*)gh4;
      const int jlo = (bid * 2320) / 96, jhi = ((bid + 1) * 2320) / 96;  // hf slice
      for (int j = tid; j < 2320; j += 1024) {
        u64t ia = ld_ag_u64(&gi2[(size_t)j * 2]);
        u64t ib = ld_ag_u64(&gi2[(size_t)j * 2 + 1]);
        u64t ha = ld_ag_u64(&gh2[(size_t)j * 2]);
        u64t hb = ld_ag_u64(&gh2[(size_t)j * 2 + 1]);
        float ir = u2f_lo(ia) + b_ih[j];
        float iz = u2f_hi(ia) + b_ih[2320 + j];
        float ig = u2f_lo(ib) + b_ih[4640 + j];
        float hr = u2f_lo(ha) + b_hh[j];
        float hz = u2f_hi(ha) + b_hh[2320 + j];
        float hg = u2f_lo(hb) + b_hh[4640 + j];
        float rr = 1.f / (1.f + expf(-(ir + hr)));
        float zz = 1.f / (1.f + expf(-(iz + hz)));
        float gg = tanhf(ig + rr * hg);
        float hold = (t == 0) ? h0[j] : ld_ag_f32(&hf_old[j]);
        float hn = (1.f - zz) * gg + zz * hold;
        s_h2[j] = f2bf(hn);
        if (j >= jlo && j < jhi) st_ag_f32(&hf_out[j], hn);   // sliced hf publish
      }
      if (tid < 16) s_h2[2320 + tid] = 0;   // keep K-pad zero
      __syncthreads();
      // publish h_new bf16: SLICED across the 96 C blocks (identical values)
      {
        const int wlo = (bid * 1168) / 96, whi = ((bid + 1) * 1168) / 96;
        if (tid < whi - wlo) {
          int w = wlo + tid;
          unsigned v = (unsigned)s_h2[2 * w] | ((unsigned)s_h2[2 * w + 1] << 16);
          st_ag_u32(hb_out32 + w, v);
        }
      }
      // l2 rows (8 per block), bf16 VALU dot from LDS
      if (wav < 8) {
        const int row = bid * 8 + wav;
        const uint4* wr = (const uint4*)(bw2 + (size_t)row * 2320);
        const uint4* hx = (const uint4*)s_h2;
        float acc = 0.f;
        for (int k = lane; k < 290; k += 64) acc += dot8bb(wr[k], hx[k]);
        acc = wred(acc);
        if (lane == 0) s_l2loc[wav] = fmaxf(acc + b2[row], 0.f);
      }
      __syncthreads();
      // z-partials
      if (tid < 192) {
        const float* w3r = W3 + (size_t)tid * 768 + bid * 8;
        float a = 0.f;
#pragma unroll
        for (int r = 0; r < 8; r++) a += w3r[r] * s_l2loc[r];
        s_a[tid] = a * s_innov[tid % 48];
      }
      __syncthreads();
      if (tid < 4) {
        float zv = 0.f;
        for (int j = 0; j < 48; j++) zv += s_a[tid * 48 + j];
        st_ag_f32(&zp[bid * 4 + tid], zv);
      }
    }
    ++ep; gbar(wsb, bid, ep, &s_ok);   // -------- SYNC 2: h/l2/z ready --------
  }
}

// ================= cooperative fp32 kernel (proven fallback) =================
__global__ __launch_bounds__(256, 2) void knet(
    const float* __restrict__ y_seq, const float* __restrict__ x0,
    const float* __restrict__ h0, const float* __restrict__ A,
    const float* __restrict__ Cm, const float* __restrict__ W1,
    const float* __restrict__ b1, const float* __restrict__ W_ih,
    const float* __restrict__ W_hh, const float* __restrict__ b_ih,
    const float* __restrict__ b_hh, const float* __restrict__ W2,
    const float* __restrict__ b2, const float* __restrict__ W3,
    const float* __restrict__ b3, float* __restrict__ out,
    float* __restrict__ ws)
{
  cg::grid_group grid = cg::this_grid();
  const int tid = threadIdx.x, lane = tid & 63, wav = tid >> 6, bid = blockIdx.x;
  const int gt = bid * 256 + tid, wave_g = bid * 4 + wav, NW = gridDim.x * 4;

  __shared__ __align__(16) float4 s_buf4[1040];
  __shared__ __align__(16) float4 s_h4[580];
  __shared__ __align__(16) float s_kgin[52];
  __shared__ float s_innov[48];
  __shared__ float s_xpost[4], s_xprior[4], s_dx[4];
  __shared__ float s_sc2, s_sc4;

  for (int t = 0; t <= T_STEPS; ++t) {
    if (t == 0) {
      if (tid < 4) s_xpost[tid] = x0[tid];
    } else {
      const float4* vv  = (const float4*)(ws + WS_V + wav * 768);
      const float4* l2v = (const float4*)(ws + WS_L2);
      float acc = 0.f;
      for (int k = lane; k < 192; k += 64) acc += dot4(vv[k], l2v[k]);
      acc = wred(acc);
      if (lane == 0)
        s_xpost[wav] = s_xprior[wav] + (acc + ws[WS_C + wav]) * 1e-4f;
    }
    __syncthreads();
    if (bid == 0 && t > 0 && tid < 4) out[tid * T_STEPS + (t - 1)] = s_xpost[tid];
    if (t == T_STEPS) return;

    if (tid < 4) {
      float xp = 0.f;
#pragma unroll
      for (int j = 0; j < 4; j++) xp += A[tid * 4 + j] * s_xpost[j];
      s_xprior[tid] = xp;
    }
    __syncthreads();
    if (tid < 48) {
      float yp = Cm[tid * 5 + 4];
#pragma unroll
      for (int j = 0; j < 4; j++) yp += Cm[tid * 5 + j] * s_xprior[j];
      s_innov[tid] = y_seq[tid * T_STEPS + t] - yp;
    }
    if (tid >= 64 && tid < 68) {
      int i = tid - 64;
      s_dx[i] = s_xpost[i] - s_xprior[i];
    }
    __syncthreads();
    if (tid == 0) {
      float s2 = 0.f;
      for (int r = 0; r < 48; r++) s2 += s_innov[r] * s_innov[r];
      s_sc2 = 1.0f / fmaxf(sqrtf(s2), 1e-12f);
      float s4 = 0.f;
      for (int i = 0; i < 4; i++) s4 += s_dx[i] * s_dx[i];
      s_sc4 = 1.0f / fmaxf(sqrtf(s4), 1e-12f);
    }
    __syncthreads();
    if (tid < 48) s_kgin[tid] = s_innov[tid] * s_sc2;
    else if (tid < 52) s_kgin[tid] = s_dx[tid - 48] * s_sc4;
    __syncthreads();

    if (gt < 4160) {
      const float4* wr  = (const float4*)(W1 + (size_t)gt * 52);
      const float4* kg4 = (const float4*)s_kgin;
      float acc = b1[gt];
#pragma unroll
      for (int k = 0; k < 13; k++) acc += dot4(wr[k], kg4[k]);
      ws[WS_L1 + gt] = fmaxf(acc, 0.f);
    }
    grid.sync();

    {
      const float* h_old = (t == 0) ? h0 : (ws + (((t & 1) == 0) ? WS_H0 : WS_H1));
      float* h_new = ws + (((t & 1) == 0) ? WS_H1 : WS_H0);
      const float4* l1g = (const float4*)(ws + WS_L1);
      for (int i = tid; i < 1040; i += 256) s_buf4[i] = l1g[i];
      const float4* hog = (const float4*)h_old;
      for (int i = tid; i < 580; i += 256) s_h4[i] = hog[i];
      __syncthreads();
      const float* s_h = (const float*)s_h4;

      for (int j = wave_g; j < 2320; j += NW) {
        const float4* r0 = (const float4*)(W_ih + (size_t)j * 4160);
        const float4* r1 = (const float4*)(W_ih + (size_t)(j + 2320) * 4160);
        const float4* r2 = (const float4*)(W_ih + (size_t)(j + 4640) * 4160);
        float a0 = 0.f, a1 = 0.f, a2 = 0.f;
#pragma unroll 4
        for (int k = lane; k < 1040; k += 64) {
          float4 x = s_buf4[k];
          a0 += dot4(r0[k], x); a1 += dot4(r1[k], x); a2 += dot4(r2[k], x);
        }
        const float4* q0 = (const float4*)(W_hh + (size_t)j * 2320);
        const float4* q1 = (const float4*)(W_hh + (size_t)(j + 2320) * 2320);
        const float4* q2 = (const float4*)(W_hh + (size_t)(j + 4640) * 2320);
        float c0 = 0.f, c1 = 0.f, c2 = 0.f;
#pragma unroll 4
        for (int k = lane; k < 580; k += 64) {
          float4 x = s_h4[k];
          c0 += dot4(q0[k], x); c1 += dot4(q1[k], x); c2 += dot4(q2[k], x);
        }
        a0 = wred(a0); a1 = wred(a1); a2 = wred(a2);
        c0 = wred(c0); c1 = wred(c1); c2 = wred(c2);
        if (lane == 0) {
          float ir = a0 + b_ih[j], iz = a1 + b_ih[j + 2320], ig = a2 + b_ih[j + 4640];
          float hr = c0 + b_hh[j], hz = c1 + b_hh[j + 2320], hg = c2 + b_hh[j + 4640];
          float rr = 1.f / (1.f + expf(-(ir + hr)));
          float zz = 1.f / (1.f + expf(-(iz + hz)));
          float gg = tanhf(ig + rr * hg);
          h_new[j] = (1.f - zz) * gg + zz * s_h[j];
        }
      }
    }
    grid.sync();

    {
      const float* h_new = ws + (((t & 1) == 0) ? WS_H1 : WS_H0);
      const float4* hv = (const float4*)h_new;
      for (int i = tid; i < 580; i += 256) s_buf4[i] = hv[i];
      __syncthreads();

      if (gt < 3072) {
        int i = gt / 768, cc = gt - i * 768;
        const float* wcol = W3 + (size_t)(i * 48) * 768 + cc;
        float acc = 0.f;
#pragma unroll 8
        for (int j = 0; j < 48; j++) acc += s_innov[j] * wcol[(size_t)j * 768];
        ws[WS_V + gt] = acc;
      } else if (gt < 3076) {
        int i = gt - 3072;
        float acc = 0.f;
        for (int j = 0; j < 48; j++) acc += s_innov[j] * b3[i * 48 + j];
        ws[WS_C + i] = acc;
      }

      for (int task = wave_g; task < 768; task += NW) {
        const float4* row = (const float4*)(W2 + (size_t)task * 2320);
        float acc = 0.f;
#pragma unroll 4
        for (int k = lane; k < 580; k += 64) acc += dot4(row[k], s_buf4[k]);
        acc = wred(acc);
        if (lane == 0) ws[WS_L2 + task] = fmaxf(acc + b2[task], 0.f);
      }
    }
    grid.sync();
  }
}

extern "C" void kernel_launch(void* const* d_in, const int* in_sizes, int n_in,
                              void* d_out, int out_size, void* d_ws, size_t ws_size,
                              hipStream_t stream) {
  const float* y_seq = (const float*)d_in[0];
  const float* x0    = (const float*)d_in[1];
  const float* h0    = (const float*)d_in[2];
  const float* A     = (const float*)d_in[3];
  const float* Cm    = (const float*)d_in[4];
  const float* W1    = (const float*)d_in[5];
  const float* b1    = (const float*)d_in[6];
  const float* W_ih  = (const float*)d_in[7];
  const float* W_hh  = (const float*)d_in[8];
  const float* b_ih  = (const float*)d_in[9];
  const float* b_hh  = (const float*)d_in[10];
  const float* W2    = (const float*)d_in[11];
  const float* b2    = (const float*)d_in[12];
  const float* W3    = (const float*)d_in[13];
  const float* b3    = (const float*)d_in[14];
  float* out = (float*)d_out;
  float* ws  = (float*)d_ws;
  char* wsb  = (char*)d_ws;

  if (ws_size >= NEED_MIN) {
    int use_w1p = (ws_size >= NEED_FULL) ? 1 : 0;
    hipFuncSetAttribute(reinterpret_cast<const void*>(knet2),
                        hipFuncAttributeMaxDynamicSharedMemorySize, DYN_LDS + 2048);
    hipMemsetAsync(wsb + O_SLOT, 0, 36864, stream);   // slots + epoch replicas
    k_pack<<<8192, 256, 0, stream>>>(W_ih, (uint4*)(wsb + O_PIH),
                                     4160, 130, 435 * 130 * 64);
    k_pack<<<8192, 256, 0, stream>>>(W_hh, (uint4*)(wsb + O_PHH),
                                     2320, 73, 435 * 73 * 64);
    k_cvt<<<512, 256, 0, stream>>>((const float4*)W2,
                                   (ushort4*)(wsb + O_W2B), N_W2 / 4);
    if (use_w1p)
      k_cvtw1<<<(4160 * 56 + 255) / 256, 256, 0, stream>>>(
          W1, (unsigned short*)(wsb + O_W1P));
    k_h0<<<10, 256, 0, stream>>>(h0, (unsigned short*)(wsb + O_HB),
                                 (unsigned short*)(wsb + O_HB + HB_STR));

    void* args[] = { &y_seq, &x0, &h0, &A, &Cm, &W1, &b1, &b_ih, &b_hh,
                     &b2, &W3, &b3, &out, &wsb, &use_w1p };
    hipError_t err = hipLaunchCooperativeKernel(
        reinterpret_cast<void*>(knet2), dim3(256), dim3(1024), args, DYN_LDS, stream);
    if (err == hipSuccess) return;
  }

  {
    void* args[] = { &y_seq, &x0, &h0, &A, &Cm, &W1, &b1, &W_ih, &W_hh,
                     &b_ih, &b_hh, &W2, &b2, &W3, &b3, &out, &ws };
    hipLaunchCooperativeKernel(
        reinterpret_cast<void*>(knet), dim3(256), dim3(256), args, 0, stream);
  }
}

// Round 18
// 10349.978 us; speedup vs baseline: 1.0587x; 1.0459x over previous
//
#include <hip/hip_runtime.h>
#include <hip/hip_cooperative_groups.h>

namespace cg = cooperative_groups;

#define T_STEPS 256
// sizes: M=4 N=48 H1=4160 HID=2320 3HID=6960 H2=768 OUT=192 KGIN=52

// ---------------- ws byte-offset layout ----------------
#define O_SLOT  0                  // 256 u32 arrival slots
#define O_EPOCH 1024               // 1 u32 epoch
#define O_ZP    2048               // 96*4 f32 z-partials
#define O_HF    6144               // 2 x 2320 f32 (h state, parity)
#define HF_STR  9280
#define O_HB    24704              // 2 x 2336 bf16 (h bf16, parity)
#define HB_STR  4672
#define O_GI4   34048              // 2320*4 f32 interleaved (r,z,g,pad)
#define O_GH4   71168              // 2320*4 f32 -> ends 108288
// packed weights: pk[job][kt][lane] 16B fragments, per-wave contiguous streams
#define O_PIH   108544             // 435 jobs * 130 kt * 1024B = 57,907,200
#define O_PHH   58015744           // 435 jobs *  73 kt * 1024B = 32,517,120
#define O_W2B   90532864           // 768*2320 bf16 row-major   =  3,563,520
#define NEED_MIN 94096384
#define O_W1P   94096384           // 4160*56 bf16 (padded W1)  =    465,920
#define NEED_FULL 94562304

#define N_W2  1781760
#define PIN_U4 (130 * 64)          // 8320 uint4 = 133,120 B pinned per block
#define DYN_LDS 133120

// legacy fp32-path offsets (float units) for fallback kernel
#define WS_L1  0
#define WS_H0  4160
#define WS_H1  6480
#define WS_L2  8800
#define WS_V   9568
#define WS_C   12640

typedef __attribute__((ext_vector_type(8))) short bf16x8;
typedef __attribute__((ext_vector_type(4))) float f32x4;
typedef unsigned long long u64t;

__device__ __forceinline__ float wred(float v) {
#pragma unroll
  for (int m = 32; m; m >>= 1) v += __shfl_xor(v, m, 64);
  return v;
}
__device__ __forceinline__ float dot4(float4 a, float4 b) {
  return a.x * b.x + a.y * b.y + a.z * b.z + a.w * b.w;
}
__device__ __forceinline__ float blo(unsigned u) {
  unsigned t = u << 16; return __builtin_bit_cast(float, t);
}
__device__ __forceinline__ float bhi(unsigned u) {
  unsigned t = u & 0xFFFF0000u; return __builtin_bit_cast(float, t);
}
__device__ __forceinline__ float dot8bb(uint4 w, uint4 x) {
  float s;
  s  = blo(w.x) * blo(x.x) + bhi(w.x) * bhi(x.x);
  s += blo(w.y) * blo(x.y) + bhi(w.y) * bhi(x.y);
  s += blo(w.z) * blo(x.z) + bhi(w.z) * bhi(x.z);
  s += blo(w.w) * blo(x.w) + bhi(w.w) * bhi(x.w);
  return s;
}
__device__ __forceinline__ unsigned short f2bf(float f) {  // RNE
  unsigned u = __builtin_bit_cast(unsigned, f);
  unsigned r = u + 0x7FFF + ((u >> 16) & 1);
  return (unsigned short)(r >> 16);
}
__device__ __forceinline__ float u2f_lo(u64t v) {
  unsigned u = (unsigned)(v & 0xFFFFFFFFull);
  return __builtin_bit_cast(float, u);
}
__device__ __forceinline__ float u2f_hi(u64t v) {
  unsigned u = (unsigned)(v >> 32);
  return __builtin_bit_cast(float, u);
}

// ---- scoped accessors: cross-block data via coherence point, no invalidates
__device__ __forceinline__ void st_ag_f32(float* p, float v) {
  __hip_atomic_store(p, v, __ATOMIC_RELAXED, __HIP_MEMORY_SCOPE_AGENT);
}
__device__ __forceinline__ float ld_ag_f32(const float* p) {
  return __hip_atomic_load(p, __ATOMIC_RELAXED, __HIP_MEMORY_SCOPE_AGENT);
}
__device__ __forceinline__ void st_ag_u32(unsigned* p, unsigned v) {
  __hip_atomic_store(p, v, __ATOMIC_RELAXED, __HIP_MEMORY_SCOPE_AGENT);
}
__device__ __forceinline__ u64t ld_ag_u64(const u64t* p) {
  return __hip_atomic_load(p, __ATOMIC_RELAXED, __HIP_MEMORY_SCOPE_AGENT);
}

// ---------- slot barrier (R11-proven): parallel release-store arrivals ----------
__device__ __forceinline__ void gbar(char* wsb, int bid, unsigned target, int* s_ok) {
  unsigned* slot  = (unsigned*)(wsb + O_SLOT);
  unsigned* epoch = (unsigned*)(wsb + O_EPOCH);
  const int tid = threadIdx.x;
  __syncthreads();
  if (bid == 0) {
    for (;;) {
      if (tid == 0) *s_ok = 1;
      __syncthreads();
      if (tid >= 1 && tid < 256) {
        if (__hip_atomic_load(&slot[tid], __ATOMIC_RELAXED, __HIP_MEMORY_SCOPE_AGENT) < target)
          *s_ok = 0;
      }
      __syncthreads();
      if (*s_ok) break;
      __builtin_amdgcn_s_sleep(2);
    }
    if (tid == 0)
      __hip_atomic_store(epoch, target, __ATOMIC_RELEASE, __HIP_MEMORY_SCOPE_AGENT);
    __syncthreads();
  } else {
    if (tid == 0) {
      __hip_atomic_store(&slot[bid], target, __ATOMIC_RELEASE, __HIP_MEMORY_SCOPE_AGENT);
      while (__hip_atomic_load(epoch, __ATOMIC_RELAXED, __HIP_MEMORY_SCOPE_AGENT) < target)
        __builtin_amdgcn_s_sleep(1);
    }
    __syncthreads();
  }
}

// ---------------- pre-pass kernels ----------------
__global__ __launch_bounds__(256) void k_pack(const float* __restrict__ W,
                                              uint4* __restrict__ dst,
                                              int K, int NKT, int n) {
  int idx = blockIdx.x * 256 + threadIdx.x;
  int stride = gridDim.x * 256;
  for (; idx < n; idx += stride) {
    int l = idx & 63;
    int u = idx >> 6;
    int kt = u % NKT;
    int job = u / NKT;
    int g = job / 145, jt = job - g * 145;
    int row = g * 2320 + jt * 16 + (l & 15);
    int col = kt * 32 + ((l >> 4) << 3);
    const float* src = W + (size_t)row * K + col;
    unsigned short o[8];
    if (col + 7 < K) {
#pragma unroll
      for (int i = 0; i < 8; i++) o[i] = f2bf(src[i]);
    } else {
#pragma unroll
      for (int i = 0; i < 8; i++) o[i] = (col + i < K) ? f2bf(src[i]) : (unsigned short)0;
    }
    uint4 v;
    v.x = (unsigned)o[0] | ((unsigned)o[1] << 16);
    v.y = (unsigned)o[2] | ((unsigned)o[3] << 16);
    v.z = (unsigned)o[4] | ((unsigned)o[5] << 16);
    v.w = (unsigned)o[6] | ((unsigned)o[7] << 16);
    dst[idx] = v;
  }
}
__global__ __launch_bounds__(256) void k_cvt(const float4* __restrict__ src,
                                             ushort4* __restrict__ dst, int n4) {
  int i = blockIdx.x * 256 + threadIdx.x, st = gridDim.x * 256;
  for (; i < n4; i += st) {
    float4 v = src[i];
    ushort4 o;
    o.x = f2bf(v.x); o.y = f2bf(v.y); o.z = f2bf(v.z); o.w = f2bf(v.w);
    dst[i] = o;
  }
}
__global__ __launch_bounds__(256) void k_cvtw1(const float* __restrict__ W1,
                                               unsigned short* __restrict__ dst) {
  int i = blockIdx.x * 256 + threadIdx.x;           // over 4160*56
  if (i < 4160 * 56) {
    int r = i / 56, c = i - r * 56;
    dst[i] = (c < 52) ? f2bf(W1[r * 52 + c]) : (unsigned short)0;
  }
}
__global__ __launch_bounds__(256) void k_h0(const float* __restrict__ h0,
                                            unsigned short* __restrict__ hb0,
                                            unsigned short* __restrict__ hb1) {
  int j = blockIdx.x * 256 + threadIdx.x;
  if (j < 2336) {
    hb1[j] = (j < 2320) ? f2bf(h0[j]) : (unsigned short)0;
    if (j >= 2320) hb0[j] = 0;
  }
}

// ================= main 2-sync kernel (256 blocks x 1024 threads) =================
// FINAL = R13 verbatim (best measured: 10,333 us). Clamped 8-deep prefetch,
// q0 job pinned in dynamic LDS, interleaved gi/gh, slot barrier, parallel
// zp gather. R14-R17 levers (barrier line-spread, NT loads, micro-overlaps)
// all measured null or negative and are excluded.
__global__ __launch_bounds__(1024, 4) void knet2(
    const float* __restrict__ y_seq, const float* __restrict__ x0,
    const float* __restrict__ h0, const float* __restrict__ A,
    const float* __restrict__ Cm, const float* __restrict__ W1,
    const float* __restrict__ b1, const float* __restrict__ b_ih,
    const float* __restrict__ b_hh, const float* __restrict__ b2,
    const float* __restrict__ W3, const float* __restrict__ b3,
    float* __restrict__ out, char* __restrict__ wsb, int use_w1p)
{
  const int tid  = threadIdx.x;
  const int lane = tid & 63;
  const int wav  = tid >> 6;
  const int bid  = blockIdx.x;

  float* zp  = (float*)(wsb + O_ZP);
  float* gi4 = (float*)(wsb + O_GI4);
  float* gh4 = (float*)(wsb + O_GH4);
  const unsigned short* bw2 = (const unsigned short*)(wsb + O_W2B);
  const uint4* w1p = (const uint4*)(wsb + O_W1P);

  extern __shared__ __align__(16) char dynsmem[];
  uint4* pin = (uint4*)dynsmem;                  // 130 kt x 64 lanes, q0 job

  __shared__ __align__(16) uint4 s_l1u[520];     // l1 bf16
  __shared__ __align__(16) uint4 s_h4u[292];     // h bf16 (MFMA operand)
  __shared__ __align__(16) unsigned short s_h2[2336];  // h_new bf16 (C)
  __shared__ float s_part[4][4][16];
  __shared__ __align__(16) unsigned short s_kgb[64];
  __shared__ __align__(16) float s_kgf[52];
  __shared__ float s_innov[48];
  __shared__ float s_a[192];
  __shared__ float s_zred[384];
  __shared__ float s_l2loc[8];
  __shared__ float s_xpost[4], s_xprior[4], s_dx[4];
  __shared__ float s_sc2, s_sc4;
  __shared__ int s_ok;

  // ---- one-time: pin this block's q0 (ih) job weights into LDS ----
  {
    const uint4* src = (const uint4*)(wsb + O_PIH) + (size_t)bid * PIN_U4;
    for (int i = tid; i < PIN_U4; i += 1024) pin[i] = src[i];
  }

  unsigned ep = 0;

  for (int t = 0; t <= T_STEPS; ++t) {
    // ======== prologue: x_post(t) from z-partials(t-1) [all blocks] ========
    if (t == 0) {
      if (tid < 4) s_xpost[tid] = x0[tid];
    } else {
      if (tid < 384) s_zred[tid] = ld_ag_f32(&zp[tid]);   // parallel gather
      __syncthreads();
      if (tid < 4) {
        float z = 0.f;
#pragma unroll 8
        for (int p = 0; p < 96; ++p) z += s_zred[p * 4 + tid];
        float cb = 0.f;
        for (int j = 0; j < 48; ++j) cb += s_innov[j] * b3[tid * 48 + j];
        float xn = s_xprior[tid] + (z + cb) * 1e-4f;
        s_xpost[tid] = xn;
        if (bid == 0) out[tid * T_STEPS + (t - 1)] = xn;
      }
    }
    __syncthreads();
    if (t == T_STEPS) return;

    // ======== small math: x_prior, innov, kg_in ========
    if (tid < 4) {
      float xpr = 0.f;
#pragma unroll
      for (int j = 0; j < 4; j++) xpr += A[tid * 4 + j] * s_xpost[j];
      s_xprior[tid] = xpr;
    }
    __syncthreads();
    if (tid < 48) {
      float yp = Cm[tid * 5 + 4];
#pragma unroll
      for (int j = 0; j < 4; j++) yp += Cm[tid * 5 + j] * s_xprior[j];
      s_innov[tid] = y_seq[tid * T_STEPS + t] - yp;
    }
    if (tid >= 64 && tid < 68) {
      int i = tid - 64;
      s_dx[i] = s_xpost[i] - s_xprior[i];
    }
    __syncthreads();
    if (tid == 0) {
      float s2 = 0.f;
      for (int r = 0; r < 48; r++) s2 += s_innov[r] * s_innov[r];
      s_sc2 = 1.0f / fmaxf(sqrtf(s2), 1e-12f);
      float s4 = 0.f;
      for (int i = 0; i < 4; i++) s4 += s_dx[i] * s_dx[i];
      s_sc4 = 1.0f / fmaxf(sqrtf(s4), 1e-12f);
    }
    __syncthreads();
    if (tid < 64) {
      float v = (tid < 48) ? s_innov[tid] * s_sc2
              : (tid < 52) ? s_dx[tid - 48] * s_sc4 : 0.f;
      s_kgb[tid] = f2bf(v);
      if (tid < 52) s_kgf[tid] = v;
    }
    // stage h(t-1) bf16 into LDS via agent loads
    {
      const u64t* hbg = (const u64t*)(wsb + O_HB + ((t + 1) & 1) * HB_STR);
      u64t* dst = (u64t*)s_h4u;
      if (tid < 584) dst[tid] = ld_ag_u64(hbg + tid);
    }
    __syncthreads();

    // ======== l1 = relu(W1 @ kg + b1), redundant per block ========
    if (use_w1p) {
      const uint4* kg4 = (const uint4*)s_kgb;
      for (int r = tid; r < 4160; r += 1024) {
        const uint4* wr = w1p + (size_t)r * 7;
        float acc = b1[r];
#pragma unroll
        for (int c = 0; c < 7; c++) acc += dot8bb(wr[c], kg4[c]);
        ((unsigned short*)s_l1u)[r] = f2bf(fmaxf(acc, 0.f));
      }
    } else {
      const float4* kg4 = (const float4*)s_kgf;
      for (int r = tid; r < 4160; r += 1024) {
        const float4* wr = (const float4*)(W1 + (size_t)r * 52);
        float acc = b1[r];
#pragma unroll
        for (int c = 0; c < 13; c++) acc += dot4(wr[c], kg4[c]);
        ((unsigned short*)s_l1u)[r] = f2bf(fmaxf(acc, 0.f));
      }
    }
    __syncthreads();

    // ======== GRU GEMV via MFMA: q0 pinned LDS; q1-3 global 8-deep CLAMPED ====
    {
      const int q  = wav >> 2;        // job slot 0..3
      const int kw = wav & 3;         // k-split
      const int job = bid + 256 * q;
      if (job < 870) {
        const int xoff = lane >> 4;
        f32x4 acc = {0.f, 0.f, 0.f, 0.f};
        if (q == 0) {
          // ---- pinned LDS path (ih job 'bid', all 130 kt resident) ----
          int kbeg = kw * 33, kend = kbeg + 33; if (kend > 130) kend = 130;
          const uint4* xs = s_l1u;
          for (int kt = kbeg; kt < kend; ++kt)
            acc = __builtin_amdgcn_mfma_f32_16x16x32_bf16(
                __builtin_bit_cast(bf16x8, pin[kt * 64 + lane]),
                __builtin_bit_cast(bf16x8, xs[kt * 4 + xoff]), acc, 0, 0, 0);
        } else {
          const int side = (job < 435) ? 0 : 1;
          const uint4* xs;
          const uint4* wp;
          int kbeg, kend;
          if (side == 0) {
            xs = s_l1u;
            kbeg = kw * 33; kend = kbeg + 33; if (kend > 130) kend = 130;
            wp = (const uint4*)(wsb + O_PIH) + ((size_t)job * 130 + kbeg) * 64 + lane;
          } else {
            xs = s_h4u;
            kbeg = kw * 19; kend = kbeg + 19; if (kend > 73) kend = 73;
            wp = (const uint4*)(wsb + O_PHH) + ((size_t)(job - 435) * 73 + kbeg) * 64 + lane;
          }
          const int last = kend - kbeg - 1;   // last valid local unit
          uint4 b0  = wp[0 * 64];
          uint4 b1r = wp[1 * 64];
          uint4 b2r = wp[2 * 64];
          uint4 b3r = wp[3 * 64];
          uint4 b4  = wp[4 * 64];
          uint4 b5  = wp[5 * 64];
          uint4 b6  = wp[6 * 64];
          uint4 b7  = wp[7 * 64];
          int kt = kbeg;
#define GSTEP(P, B) { acc = __builtin_amdgcn_mfma_f32_16x16x32_bf16( \
              __builtin_bit_cast(bf16x8, B), \
              __builtin_bit_cast(bf16x8, xs[(kt + P) * 4 + xoff]), acc, 0, 0, 0); \
              int ri = kt - kbeg + 8 + P; ri = (ri > last) ? last : ri; \
              B = wp[(size_t)ri * 64]; }
          while (kt + 8 <= kend) {
            GSTEP(0, b0) GSTEP(1, b1r) GSTEP(2, b2r) GSTEP(3, b3r)
            GSTEP(4, b4) GSTEP(5, b5)  GSTEP(6, b6)  GSTEP(7, b7)
            kt += 8;
          }
#undef GSTEP
#define TSTEP(P, B) if (kt + P < kend) acc = __builtin_amdgcn_mfma_f32_16x16x32_bf16( \
              __builtin_bit_cast(bf16x8, B), \
              __builtin_bit_cast(bf16x8, xs[(kt + P) * 4 + xoff]), acc, 0, 0, 0);
          TSTEP(0, b0) TSTEP(1, b1r) TSTEP(2, b2r) TSTEP(3, b3r)
          TSTEP(4, b4) TSTEP(5, b5)  TSTEP(6, b6)  TSTEP(7, b7)
#undef TSTEP
        }
        if ((lane & 15) == 0) {
          int rb = (lane >> 4) * 4;
#pragma unroll
          for (int i = 0; i < 4; i++) s_part[q][kw][rb + i] = acc[i];
        }
      }
    }
    __syncthreads();
    if (tid < 64) {
      int q = tid >> 4, r = tid & 15;
      int job = bid + 256 * q;
      if (job < 870) {
        float s = s_part[q][0][r] + s_part[q][1][r] + s_part[q][2][r] + s_part[q][3][r];
        if (job < 435) {
          int g = job / 145, jt = job - g * 145;
          st_ag_f32(&gi4[(size_t)(jt * 16 + r) * 4 + g], s);
        } else {
          int j2 = job - 435;
          int g = j2 / 145, jt = j2 - g * 145;
          st_ag_f32(&gh4[(size_t)(jt * 16 + r) * 4 + g], s);
        }
      }
    }
    ++ep; gbar(wsb, bid, ep, &s_ok);   // -------- SYNC 1: gi/gh ready --------

    // ======== C: gates (96 blocks, redundant), l2, z-partials ========
    if (bid < 96) {
      float* hf_out = (float*)(wsb + O_HF + (t & 1) * HF_STR);
      unsigned* hb_out32 = (unsigned*)(wsb + O_HB + (t & 1) * HB_STR);
      const float* hf_old = (const float*)(wsb + O_HF + ((t + 1) & 1) * HF_STR);
      const u64t* gi2 = (const u64t*)gi4;
      const u64t* gh2 = (const u64t*)gh4;
      for (int j = tid; j < 2320; j += 1024) {
        u64t ia = ld_ag_u64(&gi2[(size_t)j * 2]);
        u64t ib = ld_ag_u64(&gi2[(size_t)j * 2 + 1]);
        u64t ha = ld_ag_u64(&gh2[(size_t)j * 2]);
        u64t hb = ld_ag_u64(&gh2[(size_t)j * 2 + 1]);
        float ir = u2f_lo(ia) + b_ih[j];
        float iz = u2f_hi(ia) + b_ih[2320 + j];
        float ig = u2f_lo(ib) + b_ih[4640 + j];
        float hr = u2f_lo(ha) + b_hh[j];
        float hz = u2f_hi(ha) + b_hh[2320 + j];
        float hg = u2f_lo(hb) + b_hh[4640 + j];
        float rr = 1.f / (1.f + expf(-(ir + hr)));
        float zz = 1.f / (1.f + expf(-(iz + hz)));
        float gg = tanhf(ig + rr * hg);
        float hold = (t == 0) ? h0[j] : ld_ag_f32(&hf_old[j]);
        float hn = (1.f - zz) * gg + zz * hold;
        s_h2[j] = f2bf(hn);
        if (bid == 0) st_ag_f32(&hf_out[j], hn);
      }
      if (tid < 16) s_h2[2320 + tid] = 0;   // keep K-pad zero
      __syncthreads();
      // publish h_new bf16 (bid 0 only), packed u32 agent stores
      if (bid == 0 && tid < 1168) {
        unsigned v = (unsigned)s_h2[2 * tid] | ((unsigned)s_h2[2 * tid + 1] << 16);
        st_ag_u32(hb_out32 + tid, v);
      }
      // l2 rows (8 per block), bf16 VALU dot from LDS
      if (wav < 8) {
        const int row = bid * 8 + wav;
        const uint4* wr = (const uint4*)(bw2 + (size_t)row * 2320);
        const uint4* hx = (const uint4*)s_h2;
        float acc = 0.f;
        for (int k = lane; k < 290; k += 64) acc += dot8bb(wr[k], hx[k]);
        acc = wred(acc);
        if (lane == 0) s_l2loc[wav] = fmaxf(acc + b2[row], 0.f);
      }
      __syncthreads();
      // z-partials
      if (tid < 192) {
        const float* w3r = W3 + (size_t)tid * 768 + bid * 8;
        float a = 0.f;
#pragma unroll
        for (int r = 0; r < 8; r++) a += w3r[r] * s_l2loc[r];
        s_a[tid] = a * s_innov[tid % 48];
      }
      __syncthreads();
      if (tid < 4) {
        float zv = 0.f;
        for (int j = 0; j < 48; j++) zv += s_a[tid * 48 + j];
        st_ag_f32(&zp[bid * 4 + tid], zv);
      }
    }
    ++ep; gbar(wsb, bid, ep, &s_ok);   // -------- SYNC 2: h/l2/z ready --------
  }
}

// ================= cooperative fp32 kernel (proven fallback) =================
__global__ __launch_bounds__(256, 2) void knet(
    const float* __restrict__ y_seq, const float* __restrict__ x0,
    const float* __restrict__ h0, const float* __restrict__ A,
    const float* __restrict__ Cm, const float* __restrict__ W1,
    const float* __restrict__ b1, const float* __restrict__ W_ih,
    const float* __restrict__ W_hh, const float* __restrict__ b_ih,
    const float* __restrict__ b_hh, const float* __restrict__ W2,
    const float* __restrict__ b2, const float* __restrict__ W3,
    const float* __restrict__ b3, float* __restrict__ out,
    float* __restrict__ ws)
{
  cg::grid_group grid = cg::this_grid();
  const int tid = threadIdx.x, lane = tid & 63, wav = tid >> 6, bid = blockIdx.x;
  const int gt = bid * 256 + tid, wave_g = bid * 4 + wav, NW = gridDim.x * 4;

  __shared__ __align__(16) float4 s_buf4[1040];
  __shared__ __align__(16) float4 s_h4[580];
  __shared__ __align__(16) float s_kgin[52];
  __shared__ float s_innov[48];
  __shared__ float s_xpost[4], s_xprior[4], s_dx[4];
  __shared__ float s_sc2, s_sc4;

  for (int t = 0; t <= T_STEPS; ++t) {
    if (t == 0) {
      if (tid < 4) s_xpost[tid] = x0[tid];
    } else {
      const float4* vv  = (const float4*)(ws + WS_V + wav * 768);
      const float4* l2v = (const float4*)(ws + WS_L2);
      float acc = 0.f;
      for (int k = lane; k < 192; k += 64) acc += dot4(vv[k], l2v[k]);
      acc = wred(acc);
      if (lane == 0)
        s_xpost[wav] = s_xprior[wav] + (acc + ws[WS_C + wav]) * 1e-4f;
    }
    __syncthreads();
    if (bid == 0 && t > 0 && tid < 4) out[tid * T_STEPS + (t - 1)] = s_xpost[tid];
    if (t == T_STEPS) return;

    if (tid < 4) {
      float xp = 0.f;
#pragma unroll
      for (int j = 0; j < 4; j++) xp += A[tid * 4 + j] * s_xpost[j];
      s_xprior[tid] = xp;
    }
    __syncthreads();
    if (tid < 48) {
      float yp = Cm[tid * 5 + 4];
#pragma unroll
      for (int j = 0; j < 4; j++) yp += Cm[tid * 5 + j] * s_xprior[j];
      s_innov[tid] = y_seq[tid * T_STEPS + t] - yp;
    }
    if (tid >= 64 && tid < 68) {
      int i = tid - 64;
      s_dx[i] = s_xpost[i] - s_xprior[i];
    }
    __syncthreads();
    if (tid == 0) {
      float s2 = 0.f;
      for (int r = 0; r < 48; r++) s2 += s_innov[r] * s_innov[r];
      s_sc2 = 1.0f / fmaxf(sqrtf(s2), 1e-12f);
      float s4 = 0.f;
      for (int i = 0; i < 4; i++) s4 += s_dx[i] * s_dx[i];
      s_sc4 = 1.0f / fmaxf(sqrtf(s4), 1e-12f);
    }
    __syncthreads();
    if (tid < 48) s_kgin[tid] = s_innov[tid] * s_sc2;
    else if (tid < 52) s_kgin[tid] = s_dx[tid - 48] * s_sc4;
    __syncthreads();

    if (gt < 4160) {
      const float4* wr  = (const float4*)(W1 + (size_t)gt * 52);
      const float4* kg4 = (const float4*)s_kgin;
      float acc = b1[gt];
#pragma unroll
      for (int k = 0; k < 13; k++) acc += dot4(wr[k], kg4[k]);
      ws[WS_L1 + gt] = fmaxf(acc, 0.f);
    }
    grid.sync();

    {
      const float* h_old = (t == 0) ? h0 : (ws + (((t & 1) == 0) ? WS_H0 : WS_H1));
      float* h_new = ws + (((t & 1) == 0) ? WS_H1 : WS_H0);
      const float4* l1g = (const float4*)(ws + WS_L1);
      for (int i = tid; i < 1040; i += 256) s_buf4[i] = l1g[i];
      const float4* hog = (const float4*)h_old;
      for (int i = tid; i < 580; i += 256) s_h4[i] = hog[i];
      __syncthreads();
      const float* s_h = (const float*)s_h4;

      for (int j = wave_g; j < 2320; j += NW) {
        const float4* r0 = (const float4*)(W_ih + (size_t)j * 4160);
        const float4* r1 = (const float4*)(W_ih + (size_t)(j + 2320) * 4160);
        const float4* r2 = (const float4*)(W_ih + (size_t)(j + 4640) * 4160);
        float a0 = 0.f, a1 = 0.f, a2 = 0.f;
#pragma unroll 4
        for (int k = lane; k < 1040; k += 64) {
          float4 x = s_buf4[k];
          a0 += dot4(r0[k], x); a1 += dot4(r1[k], x); a2 += dot4(r2[k], x);
        }
        const float4* q0 = (const float4*)(W_hh + (size_t)j * 2320);
        const float4* q1 = (const float4*)(W_hh + (size_t)(j + 2320) * 2320);
        const float4* q2 = (const float4*)(W_hh + (size_t)(j + 4640) * 2320);
        float c0 = 0.f, c1 = 0.f, c2 = 0.f;
#pragma unroll 4
        for (int k = lane; k < 580; k += 64) {
          float4 x = s_h4[k];
          c0 += dot4(q0[k], x); c1 += dot4(q1[k], x); c2 += dot4(q2[k], x);
        }
        a0 = wred(a0); a1 = wred(a1); a2 = wred(a2);
        c0 = wred(c0); c1 = wred(c1); c2 = wred(c2);
        if (lane == 0) {
          float ir = a0 + b_ih[j], iz = a1 + b_ih[j + 2320], ig = a2 + b_ih[j + 4640];
          float hr = c0 + b_hh[j], hz = c1 + b_hh[j + 2320], hg = c2 + b_hh[j + 4640];
          float rr = 1.f / (1.f + expf(-(ir + hr)));
          float zz = 1.f / (1.f + expf(-(iz + hz)));
          float gg = tanhf(ig + rr * hg);
          h_new[j] = (1.f - zz) * gg + zz * s_h[j];
        }
      }
    }
    grid.sync();

    {
      const float* h_new = ws + (((t & 1) == 0) ? WS_H1 : WS_H0);
      const float4* hv = (const float4*)h_new;
      for (int i = tid; i < 580; i += 256) s_buf4[i] = hv[i];
      __syncthreads();

      if (gt < 3072) {
        int i = gt / 768, cc = gt - i * 768;
        const float* wcol = W3 + (size_t)(i * 48) * 768 + cc;
        float acc = 0.f;
#pragma unroll 8
        for (int j = 0; j < 48; j++) acc += s_innov[j] * wcol[(size_t)j * 768];
        ws[WS_V + gt] = acc;
      } else if (gt < 3076) {
        int i = gt - 3072;
        float acc = 0.f;
        for (int j = 0; j < 48; j++) acc += s_innov[j] * b3[i * 48 + j];
        ws[WS_C + i] = acc;
      }

      for (int task = wave_g; task < 768; task += NW) {
        const float4* row = (const float4*)(W2 + (size_t)task * 2320);
        float acc = 0.f;
#pragma unroll 4
        for (int k = lane; k < 580; k += 64) acc += dot4(row[k], s_buf4[k]);
        acc = wred(acc);
        if (lane == 0) ws[WS_L2 + task] = fmaxf(acc + b2[task], 0.f);
      }
    }
    grid.sync();
  }
}

extern "C" void kernel_launch(void* const* d_in, const int* in_sizes, int n_in,
                              void* d_out, int out_size, void* d_ws, size_t ws_size,
                              hipStream_t stream) {
  const float* y_seq = (const float*)d_in[0];
  const float* x0    = (const float*)d_in[1];
  const float* h0    = (const float*)d_in[2];
  const float* A     = (const float*)d_in[3];
  const float* Cm    = (const float*)d_in[4];
  const float* W1    = (const float*)d_in[5];
  const float* b1    = (const float*)d_in[6];
  const float* W_ih  = (const float*)d_in[7];
  const float* W_hh  = (const float*)d_in[8];
  const float* b_ih  = (const float*)d_in[9];
  const float* b_hh  = (const float*)d_in[10];
  const float* W2    = (const float*)d_in[11];
  const float* b2    = (const float*)d_in[12];
  const float* W3    = (const float*)d_in[13];
  const float* b3    = (const float*)d_in[14];
  float* out = (float*)d_out;
  float* ws  = (float*)d_ws;
  char* wsb  = (char*)d_ws;

  if (ws_size >= NEED_MIN) {
    int use_w1p = (ws_size >= NEED_FULL) ? 1 : 0;
    hipFuncSetAttribute(reinterpret_cast<const void*>(knet2),
                        hipFuncAttributeMaxDynamicSharedMemorySize, DYN_LDS + 2048);
    hipMemsetAsync(wsb + O_SLOT, 0, 2048, stream);   // slots + epoch
    k_pack<<<8192, 256, 0, stream>>>(W_ih, (uint4*)(wsb + O_PIH),
                                     4160, 130, 435 * 130 * 64);
    k_pack<<<8192, 256, 0, stream>>>(W_hh, (uint4*)(wsb + O_PHH),
                                     2320, 73, 435 * 73 * 64);
    k_cvt<<<512, 256, 0, stream>>>((const float4*)W2,
                                   (ushort4*)(wsb + O_W2B), N_W2 / 4);
    if (use_w1p)
      k_cvtw1<<<(4160 * 56 + 255) / 256, 256, 0, stream>>>(
          W1, (unsigned short*)(wsb + O_W1P));
    k_h0<<<10, 256, 0, stream>>>(h0, (unsigned short*)(wsb + O_HB),
                                 (unsigned short*)(wsb + O_HB + HB_STR));

    void* args[] = { &y_seq, &x0, &h0, &A, &Cm, &W1, &b1, &b_ih, &b_hh,
                     &b2, &W3, &b3, &out, &wsb, &use_w1p };
    hipError_t err = hipLaunchCooperativeKernel(
        reinterpret_cast<void*>(knet2), dim3(256), dim3(1024), args, DYN_LDS, stream);
    if (err == hipSuccess) return;
  }

  {
    void* args[] = { &y_seq, &x0, &h0, &A, &Cm, &W1, &b1, &W_ih, &W_hh,
                     &b_ih, &b_hh, &W2, &b2, &W3, &b3, &out, &ws };
    hipLaunchCooperativeKernel(
        reinterpret_cast<void*>(knet), dim3(256), dim3(256), args, 0, stream);
  }
}